// Round 11
// baseline (205.415 us; speedup 1.0000x reference)
//
#include <hip/hip_runtime.h>

#define Bq 16
#define Tq 2048
#define Cq 512
#define Gq 2
#define CGq 256
#define Vq 320
#define Mq 32768
#define LOSS_OFF 16777216
#define PPL_OFF  16777217
#define IDX_OFF  16777218

#define MARGIN2 6.0e-3f     // hi-only pass margin (validated rounds 6, 9, 10)
#define LIST_CAP 16384
#define LIST2_CAP 1024

// workspace byte offsets (identical to round 10)
#define WS_PCONV 0          // 512*2 doubles = 8192
#define WS_MU    8192
#define WS_RS    8320
#define WS_E2    8448       // 640 floats -> 11008
#define WS_S1    11008      // 640 floats -> 13568
#define WS_C1    13568      // 640 floats -> 16128
#define WS_LOSSF 16128
#define WS_CNT   16136
#define WS_CNT2  16140
#define WS_HIST  16144      // 640 uints -> 18704
#define WS_WSP   20480      // conv W bf16 pieces: 786432 -> 806912
// overlays inside WSP region (wsp dead after k_convM; these born later)
#define WS_LISTQ 20480      // 16384 u64 -> 151552
#define WS_PLOSS 151552     // 512 doubles -> 155648
#define WS_PL2   155648     // 2048 doubles -> 172032
#define WS_LIST2 172032     // 1024 uints -> 176128
#define WS_Z2TAB 176128     // 65536 floats -> 438272 (written by k_z2, post-convM)
// dedicated regions (validated present in round 10)
#define WS_ESPH  806912     // emb hi-only split: 327680 -> 1134592
#define WS_ZSP2  1134592    // zsp: 33554432 -> 34689024

// swizzled A-fragment slot for conv (unchanged)
#define SL(X, r) ((X) * 16 + ((r) ^ ((X) & 7)))

typedef short s16x8 __attribute__((ext_vector_type(8)));
typedef float f32x4v __attribute__((ext_vector_type(4)));

// round-to-nearest-even f32 -> bf16 bits
__device__ __forceinline__ unsigned rne16(float x) {
    unsigned u = __float_as_uint(x);
    return (u + 0x7fffu + ((u >> 16) & 1u)) >> 16;
}

// 3-piece split: x = h + m + l
__device__ __forceinline__ void bsplit3(float x, unsigned &h, unsigned &m, unsigned &l) {
    unsigned u = __float_as_uint(x);
    unsigned r1 = (u + 0x7fffu + ((u >> 16) & 1u)) & 0xffff0000u;
    h = r1 >> 16;
    float d1 = x - __uint_as_float(r1);
    unsigned u2 = __float_as_uint(d1);
    unsigned r2 = (u2 + 0x7fffu + ((u2 >> 16) & 1u)) & 0xffff0000u;
    m = r2 >> 16;
    float d2 = d1 - __uint_as_float(r2);
    unsigned u3 = __float_as_uint(d2);
    l = (u3 + 0x7fffu + ((u3 >> 16) & 1u)) >> 16;
}

// -------- merged prep: W split (bx<64) | e2/s1/c1 (bx<224) | emb hi split ------
__global__ __launch_bounds__(256) void k_prep(const float* __restrict__ w,
                                              const float* __restrict__ emb,
                                              const float* __restrict__ gw,
                                              const float* __restrict__ gb,
                                              unsigned char* __restrict__ wsp,
                                              unsigned char* __restrict__ esph,
                                              float* __restrict__ e2w,
                                              float* __restrict__ s1w,
                                              float* __restrict__ c1w) {
    int bx = blockIdx.x, tid = threadIdx.x;
    if (bx < 64) {
        int t = bx * 256 + tid;   // 0..16383
        int g = t >> 13, o = (t >> 5) & 255, ihi = t & 31;
        const float* src = w + ((size_t)(g * 256 + o)) * 256 + ihi * 8;
        float xv[8];
        *(float4*)(xv + 0) = *(const float4*)(src);
        *(float4*)(xv + 4) = *(const float4*)(src + 4);
        unsigned ph[4] = {0,0,0,0}, pm[4] = {0,0,0,0}, pl[4] = {0,0,0,0};
#pragma unroll
        for (int e = 0; e < 8; e++) {
            unsigned h, m, l;
            bsplit3(xv[e], h, m, l);
            ph[e >> 1] |= h << ((e & 1) * 16);
            pm[e >> 1] |= m << ((e & 1) * 16);
            pl[e >> 1] |= l << ((e & 1) * 16);
        }
        int kc = ihi >> 2, quad = ihi & 3, ct = o >> 4, lf = o & 15;
        size_t base = (size_t)(g * 3) * 131072 + (size_t)kc * 16384 + ct * 1024 + quad * 256 + lf * 16;
        *(uint4*)(wsp + base + 0 * 131072) = *(uint4*)ph;
        *(uint4*)(wsp + base + 1 * 131072) = *(uint4*)pm;
        *(uint4*)(wsp + base + 2 * 131072) = *(uint4*)pl;
    } else if (bx < 224) {
        // e2 (bit-identical to validated k_e2) + s1 = e2 - 2*c2, c1 = sum gw*e
        int row  = (bx - 64) * 4 + (tid >> 6);   // 0..639
        int lane = tid & 63;
        int g = row & 1;
        float4 v = *(const float4*)(emb + (size_t)row * 256 + lane * 4);
        float s = v.x * v.x + v.y * v.y + v.z * v.z + v.w * v.w;
        float4 g4 = *(const float4*)(gw + g * CGq + lane * 4);
        float4 b4 = *(const float4*)(gb + g * CGq + lane * 4);
        float c1 = g4.x * v.x + g4.y * v.y + g4.z * v.z + g4.w * v.w;
        float c2 = b4.x * v.x + b4.y * v.y + b4.z * v.z + b4.w * v.w;
#pragma unroll
        for (int m = 1; m < 64; m <<= 1) {
            s  += __shfl_xor(s, m);
            c1 += __shfl_xor(c1, m);
            c2 += __shfl_xor(c2, m);
        }
        if (lane == 0) {
            int idx = g * Vq + (row >> 1);
            e2w[idx] = s;
            s1w[idx] = s - 2.0f * c2;
            c1w[idx] = c1;
        }
    } else {
        // emb hi-only split of gw*e (values bit-identical to validated k_esplitW)
        int t = (bx - 224) * 256 + tid;   // 0..20479
        int g  = t / 10240;
        int r  = t - g * 10240;
        int kc = r / 1280;
        int r2 = r - kc * 1280;
        int ct = r2 >> 6;
        int r3 = r2 & 63;
        int kq = r3 >> 4, l15 = r3 & 15;
        int v  = ct * 16 + l15;
        int k0 = kc * 32 + kq * 8;
        const float* src = emb + ((size_t)v * 2 + g) * 256 + k0;
        const float* gws = gw + g * CGq + k0;
        float xv[8], gv[8];
        *(float4*)(xv + 0) = *(const float4*)(src);
        *(float4*)(xv + 4) = *(const float4*)(src + 4);
        *(float4*)(gv + 0) = *(const float4*)(gws);
        *(float4*)(gv + 4) = *(const float4*)(gws + 4);
        unsigned ph[4] = {0,0,0,0};
#pragma unroll
        for (int e = 0; e < 8; e++) {
            unsigned h = rne16(xv[e] * gv[e]);
            ph[e >> 1] |= h << ((e & 1) * 16);
        }
        size_t base = (size_t)g * 163840 + (size_t)kc * 20480
                    + (size_t)((ct * 4 + kq) * 16 + l15) * 16;
        *(uint4*)(esph + base) = *(uint4*)ph;
    }
}

// ------- conv GEMM (6-pass bf16 MFMA) + zsp (fragment-order bf16-hi) emit -------
__global__ __launch_bounds__(256, 2) void k_convM(const float* __restrict__ x,
    const unsigned char* __restrict__ wsp, float* __restrict__ ze,
    double* __restrict__ pconv, unsigned char* __restrict__ zsp)
{
    __shared__ unsigned char lds[73728];   // Bs 48KB | As 24KB ; epilogue: t16 67.6KB
    __shared__ double reds[4], redq[4];
    uint4* Bs = (uint4*)lds;
    uint4* As = (uint4*)(lds + 49152);

    int tid = threadIdx.x, bx = blockIdx.x;
    int mt = bx >> 1, g = bx & 1;
    int m0 = mt * 128;
    int w = tid >> 6, lane = tid & 63;
    int quad = lane >> 4, l15 = lane & 15;
    int arow = tid >> 1, ah = tid & 1;
    int aw = arow >> 5, art = (arow >> 4) & 1, ar = arow & 15;
    const float* xrow = x + (size_t)(m0 + arow) * Cq + g * CGq + ah * 16;
    const unsigned char* wslab = wsp + (size_t)(g * 3) * 131072;

    f32x4v zero4 = {0.f, 0.f, 0.f, 0.f};
    f32x4v acc[2][16];
#pragma unroll
    for (int i = 0; i < 2; i++)
#pragma unroll
        for (int j = 0; j < 16; j++) acc[i][j] = zero4;

    for (int kc = 0; kc < 8; kc++) {
        if (kc) __syncthreads();
#pragma unroll
        for (int j = 0; j < 12; j++) {
            int L = (w * 12 + j) * 1024 + lane * 16;
            int p = L >> 14, r = L & 16383;
            __builtin_amdgcn_global_load_lds(
                (const __attribute__((address_space(1))) void*)(wslab + (size_t)p * 131072 + (size_t)kc * 16384 + r),
                (__attribute__((address_space(3))) void*)(lds + L), 16, 0, 0);
        }
        float xv[16];
        *(float4*)(xv + 0)  = *(const float4*)(xrow + kc * 32 + 0);
        *(float4*)(xv + 4)  = *(const float4*)(xrow + kc * 32 + 4);
        *(float4*)(xv + 8)  = *(const float4*)(xrow + kc * 32 + 8);
        *(float4*)(xv + 12) = *(const float4*)(xrow + kc * 32 + 12);
#pragma unroll
        for (int ii = 0; ii < 2; ii++) {
            unsigned ph[4] = {0,0,0,0}, pm[4] = {0,0,0,0}, pl[4] = {0,0,0,0};
#pragma unroll
            for (int e = 0; e < 8; e++) {
                unsigned h, m, l;
                bsplit3(xv[ii * 8 + e], h, m, l);
                ph[e >> 1] |= h << ((e & 1) * 16);
                pm[e >> 1] |= m << ((e & 1) * 16);
                pl[e >> 1] |= l << ((e & 1) * 16);
            }
            int aq = ah * 2 + ii;
            As[SL(((0 * 4 + aw) * 2 + art) * 4 + aq, ar)] = *(uint4*)ph;
            As[SL(((1 * 4 + aw) * 2 + art) * 4 + aq, ar)] = *(uint4*)pm;
            As[SL(((2 * 4 + aw) * 2 + art) * 4 + aq, ar)] = *(uint4*)pl;
        }
        __syncthreads();
        s16x8 afr[3][2];
#pragma unroll
        for (int p = 0; p < 3; p++)
#pragma unroll
            for (int rt = 0; rt < 2; rt++)
                afr[p][rt] = __builtin_bit_cast(s16x8,
                    As[SL(((p * 4 + w) * 2 + rt) * 4 + quad, l15)]);
#pragma unroll
        for (int ct = 0; ct < 16; ct++) {
            s16x8 b0 = __builtin_bit_cast(s16x8, Bs[0 * 1024 + ct * 64 + quad * 16 + l15]);
            s16x8 b1 = __builtin_bit_cast(s16x8, Bs[1 * 1024 + ct * 64 + quad * 16 + l15]);
            s16x8 b2 = __builtin_bit_cast(s16x8, Bs[2 * 1024 + ct * 64 + quad * 16 + l15]);
#pragma unroll
            for (int rt = 0; rt < 2; rt++) {
                acc[rt][ct] = __builtin_amdgcn_mfma_f32_16x16x32_bf16(afr[0][rt], b0, acc[rt][ct], 0, 0, 0);
                acc[rt][ct] = __builtin_amdgcn_mfma_f32_16x16x32_bf16(afr[1][rt], b0, acc[rt][ct], 0, 0, 0);
                acc[rt][ct] = __builtin_amdgcn_mfma_f32_16x16x32_bf16(afr[2][rt], b0, acc[rt][ct], 0, 0, 0);
                acc[rt][ct] = __builtin_amdgcn_mfma_f32_16x16x32_bf16(afr[0][rt], b1, acc[rt][ct], 0, 0, 0);
                acc[rt][ct] = __builtin_amdgcn_mfma_f32_16x16x32_bf16(afr[1][rt], b1, acc[rt][ct], 0, 0, 0);
                acc[rt][ct] = __builtin_amdgcn_mfma_f32_16x16x32_bf16(afr[0][rt], b2, acc[rt][ct], 0, 0, 0);
            }
        }
    }

    float s = 0.f, q = 0.f;
    float* zb = ze + (size_t)m0 * Cq + g * CGq;
#pragma unroll
    for (int rt = 0; rt < 2; rt++)
#pragma unroll
    for (int ct = 0; ct < 16; ct++)
#pragma unroll
    for (int j = 0; j < 4; j++) {
        float v = acc[rt][ct][j];
        zb[(size_t)(w * 32 + rt * 16 + quad * 4 + j) * Cq + ct * 16 + l15] = v;
        s += v;
        q = __builtin_fmaf(v, v, q);
    }
    double ds = (double)s, dq = (double)q;
#pragma unroll
    for (int m = 1; m < 64; m <<= 1) { ds += __shfl_xor(ds, m); dq += __shfl_xor(dq, m); }
    if (lane == 0) { reds[w] = ds; redq[w] = dq; }
    __syncthreads();
    if (tid == 0) {
        pconv[bx * 2 + 0] = reds[0] + reds[1] + reds[2] + reds[3];
        pconv[bx * 2 + 1] = redq[0] + redq[1] + redq[2] + redq[3];
    }

    // ---- zsp emit: rne16(ze) in distA A-fragment order (validated rounds 9/10) ----
    {
        unsigned short* t16 = (unsigned short*)lds;
#pragma unroll
        for (int rt = 0; rt < 2; rt++)
#pragma unroll
        for (int ct = 0; ct < 16; ct++)
#pragma unroll
        for (int j = 0; j < 4; j++)
            t16[w * 8448 + (rt * 16 + quad * 4 + j) * 264 + ct * 16 + l15] =
                (unsigned short)rne16(acc[rt][ct][j]);
        __syncthreads();
        uint4* zt = (uint4*)(zsp + (size_t)bx * 65536);
        int rr = lane & 15, kq = lane >> 4;
#pragma unroll
        for (int kc8 = 0; kc8 < 8; kc8++)
#pragma unroll
        for (int rt = 0; rt < 2; rt++) {
            uint4 vf = *(uint4*)&t16[w * 8448 + (rt * 16 + rr) * 264 + kc8 * 32 + kq * 8];
            zt[((kc8 * 4 + w) * 2 + rt) * 64 + lane] = vf;
        }
    }
}

// ---------------- per-(b,g) mean/rstd ----------------
__global__ __launch_bounds__(256) void k_stats(const double* __restrict__ pconv,
                                               float* __restrict__ muw,
                                               float* __restrict__ rsw) {
    int tid = threadIdx.x;
    int bg = tid >> 3, r = tid & 7;
    int b = bg >> 1, g = bg & 1;
    double s = 0.0, q = 0.0;
    for (int j = r; j < 16; j += 8) {
        int pi = (b * 16 + j) * 2 + g;
        s += pconv[pi * 2 + 0];
        q += pconv[pi * 2 + 1];
    }
#pragma unroll
    for (int m = 1; m < 8; m <<= 1) { s += __shfl_xor(s, m); q += __shfl_xor(q, m); }
    if (r == 0) {
        double mu = s / 524288.0;
        double var = q / 524288.0 - mu * mu;
        double rs = 1.0 / sqrt(var + 1e-5);
        muw[bg] = (float)mu;
        rsw[bg] = (float)rs;
    }
}

// ---------------- per-row z2 = sum(zn^2), coalesced streaming ----------------
__global__ __launch_bounds__(256) void k_z2(const float* __restrict__ ze,
    const float* __restrict__ gw, const float* __restrict__ gb,
    const float* __restrict__ muw, const float* __restrict__ rsw,
    float* __restrict__ z2tab)
{
    int tid = threadIdx.x, lane = tid & 63;
    int gwid = blockIdx.x * 4 + (tid >> 6);   // 0..4095
    for (int rr = 0; rr < 16; rr++) {
        int q = gwid * 16 + rr;
        int m = q >> 1, g = q & 1;
        int bg = (m >> 11) * 2 + g;
        float muf = muw[bg], rsf = rsw[bg];
        float4 z  = *(const float4*)(ze + (size_t)m * Cq + g * CGq + lane * 4);
        float4 gv = *(const float4*)(gw + g * CGq + lane * 4);
        float4 bv = *(const float4*)(gb + g * CGq + lane * 4);
        float zn0 = (z.x - muf) * rsf * gv.x + bv.x;
        float zn1 = (z.y - muf) * rsf * gv.y + bv.y;
        float zn2 = (z.z - muf) * rsf * gv.z + bv.z;
        float zn3 = (z.w - muf) * rsf * gv.w + bv.w;
        float s = zn0 * zn0;
        s = __builtin_fmaf(zn1, zn1, s);
        s = __builtin_fmaf(zn2, zn2, s);
        s = __builtin_fmaf(zn3, zn3, s);
#pragma unroll
        for (int mm = 1; mm < 64; mm <<= 1) s += __shfl_xor(s, mm);
        if (lane == 0) z2tab[q] = s;
    }
}

// ---- approx distance: barrier-free, register-direct loads, folded scoring ----
// A from zsp (L3-resident), B from esph (L2-resident): per-lane coalesced
// global_load_dwordx4 straight to VGPRs; no LDS staging, no __syncthreads in
// the main loop -> waves free-run, compiler pipelines loads under MFMAs.
__global__ __launch_bounds__(256, 2) void k_distA(const unsigned char* __restrict__ zsp,
    const unsigned char* __restrict__ esph,
    const float* __restrict__ muw, const float* __restrict__ rsw,
    const float* __restrict__ s1w, const float* __restrict__ c1w,
    const float* __restrict__ z2tab,
    float* dout,
    unsigned* __restrict__ cntw, unsigned* __restrict__ cnt2w,
    unsigned long long* __restrict__ listq, unsigned* __restrict__ list2,
    unsigned* __restrict__ hist, double* __restrict__ ploss)
{
    __shared__ float s0s[Vq];
    __shared__ double redp[4];

    int tid = threadIdx.x, bx = blockIdx.x;
    int mt = bx >> 1, g = bx & 1;
    int m0 = mt * 128;
    int bg = (m0 >> 11) * 2 + g;
    float muf = muw[bg], rsf = rsw[bg];
    float beta = 2.0f * rsf;
    float alpha = beta * muf;
    int w = tid >> 6, lane = tid & 63;
    int quad = lane >> 4, l15 = lane & 15;

    for (int i = tid; i < Vq; i += 256)
        s0s[i] = s1w[g * Vq + i] + alpha * c1w[g * Vq + i];
    __syncthreads();

    const uint4* zt    = (const uint4*)(zsp + (size_t)bx * 65536);
    const uint4* ebase = (const uint4*)(esph + (size_t)g * 163840);

    f32x4v zero4 = {0.f, 0.f, 0.f, 0.f};
    f32x4v acc[2][20];
#pragma unroll
    for (int i = 0; i < 2; i++)
#pragma unroll
        for (int j = 0; j < 20; j++) acc[i][j] = zero4;

    for (int kc8 = 0; kc8 < 8; kc8++) {
        // A fragments: same slots round-10 read via LDS -> bit-identical values
        s16x8 a0 = __builtin_bit_cast(s16x8, zt[(kc8 * 4 + w) * 128 + lane]);
        s16x8 a1 = __builtin_bit_cast(s16x8, zt[(kc8 * 4 + w) * 128 + 64 + lane]);
        // B fragments: whole chunk batch-loaded to registers (coalesced 1KB/wave)
        s16x8 bfr[20];
#pragma unroll
        for (int ct = 0; ct < 20; ct++)
            bfr[ct] = __builtin_bit_cast(s16x8,
                ebase[kc8 * 1280 + (ct * 4 + quad) * 16 + l15]);
#pragma unroll
        for (int ct = 0; ct < 20; ct++) {
            acc[0][ct] = __builtin_amdgcn_mfma_f32_16x16x32_bf16(a0, bfr[ct], acc[0][ct], 0, 0, 0);
            acc[1][ct] = __builtin_amdgcn_mfma_f32_16x16x32_bf16(a1, bfr[ct], acc[1][ct], 0, 0, 0);
        }
    }

    // ---- epilogue: approx argmin + margin extraction + loss for 1-cand rows ----
    // (verbatim round 10; acc values bit-identical)
    double lacc = 0.0;
#pragma unroll
    for (int rt = 0; rt < 2; rt++)
#pragma unroll
    for (int j = 0; j < 4; j++) {
        float m1 = 3.402823466e+38f; int i1 = 0;
#pragma unroll
        for (int ct = 0; ct < 20; ct++) {
            float d2a = s0s[ct * 16 + l15] - beta * acc[rt][ct][j];
            if (d2a < m1) { m1 = d2a; i1 = ct * 16 + l15; }
        }
#pragma unroll
        for (int mm = 1; mm < 16; mm <<= 1) {
            float ov = __shfl_xor(m1, mm);
            int   oi = __shfl_xor(i1, mm);
            if (ov < m1 || (ov == m1 && oi < i1)) { m1 = ov; i1 = oi; }
        }
        float thr = m1 + MARGIN2;
        unsigned mask = 0;
#pragma unroll
        for (int ct = 0; ct < 20; ct++) {
            float d2a = s0s[ct * 16 + l15] - beta * acc[rt][ct][j];
            if (d2a <= thr) mask |= (1u << ct);
        }
        int cnt = __popc(mask);
#pragma unroll
        for (int mm = 1; mm < 16; mm <<= 1) cnt += __shfl_xor(cnt, mm);
        int mrow = m0 + w * 32 + rt * 16 + quad * 4 + j;
        unsigned q = (unsigned)mrow * 2u + (unsigned)g;
        unsigned flag = 0;
        if (cnt > 1) {
            if ((i1 & 15) == l15) mask &= ~(1u << (i1 >> 4));   // best is implicit
            int cl2 = __popc(mask);
            int inc = cl2;
#pragma unroll
            for (int off = 1; off < 16; off <<= 1) {
                int t = __shfl_up(inc, off, 16);
                if (l15 >= off) inc += t;
            }
            int pre = inc - cl2;
            if (cnt <= 5) {
                int pos_ = 0;
                if (l15 == 0) pos_ = (int)atomicAdd(cntw, 1u);
                pos_ = __shfl(pos_, 0, 16);
                if ((unsigned)pos_ < LIST_CAP) {
                    flag = 512u;
                    unsigned long long contrib = 0ull;
                    unsigned mm2 = mask; int k = pre;
                    while (mm2) {
                        int ct2 = __ffs(mm2) - 1; mm2 &= mm2 - 1;
                        contrib |= ((unsigned long long)(unsigned)(ct2 * 16 + l15)) << (20 + 9 * k);
                        k++;
                    }
#pragma unroll
                    for (int mm = 1; mm < 16; mm <<= 1)
                        contrib |= __shfl_xor(contrib, mm);
                    if (l15 == 0)
                        listq[pos_] = (unsigned long long)q
                                    | ((unsigned long long)(unsigned)cnt << 17) | contrib;
                }
            } else {
                if (l15 == 0) {
                    unsigned p2 = atomicAdd(cnt2w, 1u);
                    if (p2 < LIST2_CAP) { list2[p2] = q; flag = 512u; }
                }
            }
        }
        if (l15 == 0) {
            if (flag) {
                dout[IDX_OFF + q] = __uint_as_float((unsigned)i1 | flag);
            } else {
                dout[IDX_OFF + q] = (float)i1;
                atomicAdd(&hist[g * Vq + i1], 1u);
                lacc += (double)z2tab[q] + (double)m1;
            }
        }
    }
#pragma unroll
    for (int mm = 1; mm < 64; mm <<= 1) lacc += __shfl_xor(lacc, mm);
    if (lane == 0) redp[w] = lacc;
    __syncthreads();
    if (tid == 0) ploss[bx] = redp[0] + redp[1] + redp[2] + redp[3];
}

// -------- exact resolve among <=5 stored candidates + full-scan fallback -------
__global__ __launch_bounds__(256) void k_exF(const float* __restrict__ emb,
    const float* __restrict__ gw, const float* __restrict__ gb,
    const float* __restrict__ muw, const float* __restrict__ rsw,
    const float* __restrict__ e2w, float* dout,
    unsigned* __restrict__ hist, double* __restrict__ ploss2,
    const unsigned long long* __restrict__ listq, const unsigned* __restrict__ cntw,
    double* __restrict__ lossf,
    const unsigned* __restrict__ cnt2w, const unsigned* __restrict__ list2)
{
    int tid = threadIdx.x, lane = tid & 63;
    int gwid = blockIdx.x * 4 + (tid >> 6);
    int cslot = lane >> 2, j = lane & 3;
    unsigned nn = *cntw; if (nn > LIST_CAP) nn = LIST_CAP;
    int n = (int)nn;
    double lacc = 0.0;
    for (int it = gwid; it < n; it += 2048) {
        unsigned long long e = listq[it];
        unsigned q = (unsigned)(e & 0x1FFFFull);
        int cnt = (int)((e >> 17) & 7u);
        int m = (int)(q >> 1), g = (int)(q & 1u);
        int bg = (m >> 11) * 2 + g;
        float muf = muw[bg], rsf = rsw[bg];
        int v = (int)(__float_as_uint(dout[IDX_OFF + q]) & 511u);
        if (cslot >= 1 && cslot < cnt)
            v = (int)((e >> (20 + 9 * (cslot - 1))) & 511ull);
        const float* zb  = dout + (size_t)m * Cq + g * CGq;
        const float* gwb = gw + g * CGq;
        const float* gbb = gb + g * CGq;
        const float* eb  = emb + ((size_t)v * Gq + g) * CGq;
        float z2p = 0.f, dp = 0.f;
        for (int kc = 0; kc < 16; kc++) {
            int k0 = kc * 16 + j * 4;
            float4 z  = *(const float4*)(zb + k0);
            float4 gv = *(const float4*)(gwb + k0);
            float4 bv = *(const float4*)(gbb + k0);
            float4 e4 = *(const float4*)(eb + k0);
            float zn0 = __fadd_rn(__fmul_rn(__fmul_rn(__fsub_rn(z.x, muf), rsf), gv.x), bv.x);
            float zn1 = __fadd_rn(__fmul_rn(__fmul_rn(__fsub_rn(z.y, muf), rsf), gv.y), bv.y);
            float zn2 = __fadd_rn(__fmul_rn(__fmul_rn(__fsub_rn(z.z, muf), rsf), gv.z), bv.z);
            float zn3 = __fadd_rn(__fmul_rn(__fmul_rn(__fsub_rn(z.w, muf), rsf), gv.w), bv.w);
            z2p = __builtin_fmaf(zn0, zn0, z2p);
            z2p = __builtin_fmaf(zn1, zn1, z2p);
            z2p = __builtin_fmaf(zn2, zn2, z2p);
            z2p = __builtin_fmaf(zn3, zn3, z2p);
            dp = __builtin_fmaf(zn0, e4.x, dp);
            dp = __builtin_fmaf(zn1, e4.y, dp);
            dp = __builtin_fmaf(zn2, e4.z, dp);
            dp = __builtin_fmaf(zn3, e4.w, dp);
        }
        z2p += __shfl_xor(z2p, 1); z2p += __shfl_xor(z2p, 2);
        dp  += __shfl_xor(dp, 1);  dp  += __shfl_xor(dp, 2);
        float d2 = __fadd_rn(__fsub_rn(z2p, 2.0f * dp), e2w[g * Vq + v]);
#pragma unroll
        for (int mm = 4; mm < 64; mm <<= 1) {
            float od = __shfl_xor(d2, mm);
            int   ov = __shfl_xor(v, mm);
            if (od < d2 || (od == d2 && ov < v)) { d2 = od; v = ov; }
        }
        if (lane == 0) {
            dout[IDX_OFF + q] = (float)v;
            atomicAdd(&hist[g * Vq + v], 1u);
            lacc += (double)d2;
        }
    }
    if (lane == 0) ploss2[gwid] = lacc;

    // ---- full-scan fallback for >5-candidate rows (expected ~empty) ----
    unsigned nn2 = *cnt2w; if (nn2 > LIST2_CAP) nn2 = LIST2_CAP;
    int n2 = (int)nn2;
    for (int it = gwid; it < n2; it += 2048) {
        int q = (int)list2[it];
        int m = q >> 1, g = q & 1;
        int bg = (m >> 11) * 2 + g;
        float muf = muw[bg], rsf = rsw[bg];
        const float* zb = dout + (size_t)m * Cq + g * CGq;
        int k0 = lane * 4;
        float4 z  = *(const float4*)(zb + k0);
        float4 gv = *(const float4*)(gw + g * CGq + k0);
        float4 bv = *(const float4*)(gb + g * CGq + k0);
        float zn0 = __fadd_rn(__fmul_rn(__fmul_rn(__fsub_rn(z.x, muf), rsf), gv.x), bv.x);
        float zn1 = __fadd_rn(__fmul_rn(__fmul_rn(__fsub_rn(z.y, muf), rsf), gv.y), bv.y);
        float zn2 = __fadd_rn(__fmul_rn(__fmul_rn(__fsub_rn(z.z, muf), rsf), gv.z), bv.z);
        float zn3 = __fadd_rn(__fmul_rn(__fmul_rn(__fsub_rn(z.w, muf), rsf), gv.w), bv.w);
        float s = 0.f;
        for (int kc = 0; kc < 16; kc++) {
            int src = (lane & 3) + kc * 4;
            float a0 = __shfl(zn0, src), a1 = __shfl(zn1, src);
            float a2 = __shfl(zn2, src), a3 = __shfl(zn3, src);
            s = __builtin_fmaf(a0, a0, s);
            s = __builtin_fmaf(a1, a1, s);
            s = __builtin_fmaf(a2, a2, s);
            s = __builtin_fmaf(a3, a3, s);
        }
        s += __shfl_xor(s, 1); s += __shfl_xor(s, 2);
        float z2 = s;
        float m1 = 3.402823466e+38f; int i1 = 0;
        for (int v = 0; v < Vq; v += 2) {
            const float* e0 = emb + ((size_t)v * Gq + g) * CGq + k0;
            float4 ea = *(const float4*)e0;
            float4 eb4 = *(const float4*)(e0 + Gq * CGq);
            float da = zn0 * ea.x;  da = __builtin_fmaf(zn1, ea.y, da);
            da = __builtin_fmaf(zn2, ea.z, da); da = __builtin_fmaf(zn3, ea.w, da);
            float db = zn0 * eb4.x; db = __builtin_fmaf(zn1, eb4.y, db);
            db = __builtin_fmaf(zn2, eb4.z, db); db = __builtin_fmaf(zn3, eb4.w, db);
#pragma unroll
            for (int mm = 1; mm < 64; mm <<= 1) { da += __shfl_xor(da, mm); db += __shfl_xor(db, mm); }
            float d2a = __fadd_rn(__fsub_rn(z2, 2.0f * da), e2w[g * Vq + v]);
            float d2b = __fadd_rn(__fsub_rn(z2, 2.0f * db), e2w[g * Vq + v + 1]);
            if (d2a < m1) { m1 = d2a; i1 = v; }
            if (d2b < m1) { m1 = d2b; i1 = v + 1; }
        }
        if (lane == 0) {
            dout[IDX_OFF + q] = (float)i1;
            atomicAdd(&hist[g * Vq + i1], 1u);
            atomicAdd(lossf, (double)m1);
        }
    }
}

// ---------------- gather ----------------
__global__ __launch_bounds__(256) void k_out(const float* __restrict__ emb, float* dout) {
    size_t u = (size_t)blockIdx.x * 256 + threadIdx.x;
    size_t pos = u * 4;
    int m = (int)(pos >> 9);
    int c = (int)(pos & 511);
    int g = c >> 8, d = c & 255;
    int v = (int)dout[IDX_OFF + (size_t)m * Gq + g];
    float4 o = *(const float4*)(emb + ((size_t)(v * 2 + g)) * 256 + d);
    *(float4*)(dout + pos) = o;
}

// ---------------- finalize loss + perplexity ----------------
__global__ __launch_bounds__(256) void k_final(const double* __restrict__ ploss,
                                               const double* __restrict__ ploss2,
                                               const double* __restrict__ lossf,
                                               const unsigned* __restrict__ hist,
                                               float* dout) {
    __shared__ double redl[4], red0[4], red1[4];
    int tid = threadIdx.x;
    double s = 0.0;
    for (int i = tid; i < 512; i += 256) s += ploss[i];
    for (int i = tid; i < 2048; i += 256) s += ploss2[i];
#pragma unroll
    for (int m = 1; m < 64; m <<= 1) s += __shfl_xor(s, m);
    double e0 = 0.0, e1 = 0.0;
    for (int pid = tid; pid < 640; pid += 256) {
        double p = (double)hist[pid] * (1.0 / 32768.0);
        double t = p * log(p + 1e-7);
        if (pid < 320) e0 += t; else e1 += t;
    }
#pragma unroll
    for (int m = 1; m < 64; m <<= 1) { e0 += __shfl_xor(e0, m); e1 += __shfl_xor(e1, m); }
    int lane = tid & 63, wv_ = tid >> 6;
    if (lane == 0) { redl[wv_] = s; red0[wv_] = e0; red1[wv_] = e1; }
    __syncthreads();
    if (tid == 0) {
        double S  = redl[0] + redl[1] + redl[2] + redl[3] + *lossf;
        double E0 = red0[0] + red0[1] + red0[2] + red0[3];
        double E1 = red1[0] + red1[1] + red1[2] + red1[3];
        dout[LOSS_OFF] = (float)(1.25 * S / 16777216.0);
        dout[PPL_OFF]  = (float)(exp(-E0) + exp(-E1));
    }
}

extern "C" void kernel_launch(void* const* d_in, const int* in_sizes, int n_in,
                              void* d_out, int out_size, void* d_ws, size_t ws_size,
                              hipStream_t stream) {
    const float* x   = (const float*)d_in[0];
    const float* w   = (const float*)d_in[1];
    const float* gw  = (const float*)d_in[2];
    const float* gb  = (const float*)d_in[3];
    const float* emb = (const float*)d_in[4];
    float* dout = (float*)d_out;
    char* ws = (char*)d_ws;
    double* pconv   = (double*)(ws + WS_PCONV);
    float* muw      = (float*)(ws + WS_MU);
    float* rsw      = (float*)(ws + WS_RS);
    float* e2w      = (float*)(ws + WS_E2);
    float* s1w      = (float*)(ws + WS_S1);
    float* c1w      = (float*)(ws + WS_C1);
    double* lossf   = (double*)(ws + WS_LOSSF);
    unsigned* cntw  = (unsigned*)(ws + WS_CNT);
    unsigned* cnt2w = (unsigned*)(ws + WS_CNT2);
    unsigned* hist  = (unsigned*)(ws + WS_HIST);
    unsigned char* wsp = (unsigned char*)(ws + WS_WSP);
    unsigned long long* listq = (unsigned long long*)(ws + WS_LISTQ);
    double* ploss   = (double*)(ws + WS_PLOSS);
    double* ploss2  = (double*)(ws + WS_PL2);
    unsigned* list2 = (unsigned*)(ws + WS_LIST2);
    float* z2tab    = (float*)(ws + WS_Z2TAB);
    unsigned char* esph = (unsigned char*)(ws + WS_ESPH);
    unsigned char* zsp  = (unsigned char*)(ws + WS_ZSP2);

    hipMemsetAsync(ws + WS_LOSSF, 0, 2576, stream);   // lossf + cnt + cnt2 + hist
    k_prep<<<304, 256, 0, stream>>>(w, emb, gw, gb, wsp, esph, e2w, s1w, c1w);
    k_convM<<<512, 256, 0, stream>>>(x, wsp, dout, pconv, zsp);   // ze f32 + zsp frags
    k_stats<<<1, 256, 0, stream>>>(pconv, muw, rsw);
    k_z2<<<1024, 256, 0, stream>>>(dout, gw, gb, muw, rsw, z2tab);
    k_distA<<<512, 256, 0, stream>>>(zsp, esph, muw, rsw, s1w, c1w, z2tab, dout,
                                     cntw, cnt2w, listq, list2, hist, ploss);
    k_exF<<<512, 256, 0, stream>>>(emb, gw, gb, muw, rsw, e2w, dout, hist, ploss2,
                                   listq, cntw, lossf, cnt2w, list2);
    k_out<<<16384, 256, 0, stream>>>(emb, dout);
    k_final<<<1, 256, 0, stream>>>(ploss, ploss2, lossf, hist, dout);
}

// Round 12
// 191.866 us; speedup vs baseline: 1.0706x; 1.0706x over previous
//
#include <hip/hip_runtime.h>

#define Bq 16
#define Tq 2048
#define Cq 512
#define Gq 2
#define CGq 256
#define Vq 320
#define Mq 32768
#define LOSS_OFF 16777216
#define PPL_OFF  16777217
#define IDX_OFF  16777218

#define MARGIN2 8.0e-3f     // hi-only margin (6.6 sigma of score-diff error)
#define LIST_CAP 16384
#define LIST2_CAP 1024

// workspace byte offsets (round-8 layout, validated)
#define WS_PCONV 0          // 512*2 doubles
#define WS_PLOSS 16384      // 512 doubles -> 20480
#define WS_MU    49152
#define WS_RS    49280
#define WS_E2    49408      // 640 floats -> 51968
#define WS_LOSSF 51968
#define WS_CNT   51976
#define WS_CNT2  51980
#define WS_HIST  51984      // 640 uints -> 54544
#define WS_PL2   54544      // 2048 doubles -> 70928
#define WS_LIST2 70928      // 1024 uints -> 75024
#define WS_WSP   131072     // conv W bf16 pieces: 786432 -> 917504
#define WS_LISTQ 917504     // 16384 u64 -> 1048576
#define WS_ESP   1048576    // emb hi split (hi slab layout of round 8): 655360 region

// swizzled A-fragment slot: X = fragment id, r = row 0..15  (2-way max bank alias)
#define SL(X, r) ((X) * 16 + ((r) ^ ((X) & 7)))

typedef short s16x8 __attribute__((ext_vector_type(8)));
typedef float f32x4v __attribute__((ext_vector_type(4)));

// round-to-nearest-even f32 -> bf16 bits
__device__ __forceinline__ unsigned rne16(float x) {
    unsigned u = __float_as_uint(x);
    return (u + 0x7fffu + ((u >> 16) & 1u)) >> 16;
}

// 3-piece split: x = h + m + l
__device__ __forceinline__ void bsplit3(float x, unsigned &h, unsigned &m, unsigned &l) {
    unsigned u = __float_as_uint(x);
    unsigned r1 = (u + 0x7fffu + ((u >> 16) & 1u)) & 0xffff0000u;
    h = r1 >> 16;
    float d1 = x - __uint_as_float(r1);
    unsigned u2 = __float_as_uint(d1);
    unsigned r2 = (u2 + 0x7fffu + ((u2 >> 16) & 1u)) & 0xffff0000u;
    m = r2 >> 16;
    float d2 = d1 - __uint_as_float(r2);
    unsigned u3 = __float_as_uint(d2);
    l = (u3 + 0x7fffu + ((u3 >> 16) & 1u)) >> 16;
}

// ---------------- merged prep: W split (bx<64) | e2 (bx<224) | emb hi split ----
__global__ __launch_bounds__(256) void k_prep(const float* __restrict__ w,
                                              const float* __restrict__ emb,
                                              unsigned char* __restrict__ wsp,
                                              unsigned char* __restrict__ esp,
                                              float* __restrict__ e2w) {
    int bx = blockIdx.x, tid = threadIdx.x;
    if (bx < 64) {
        int t = bx * 256 + tid;   // 0..16383
        int g = t >> 13, o = (t >> 5) & 255, ihi = t & 31;
        const float* src = w + ((size_t)(g * 256 + o)) * 256 + ihi * 8;
        float xv[8];
        *(float4*)(xv + 0) = *(const float4*)(src);
        *(float4*)(xv + 4) = *(const float4*)(src + 4);
        unsigned ph[4] = {0,0,0,0}, pm[4] = {0,0,0,0}, pl[4] = {0,0,0,0};
#pragma unroll
        for (int e = 0; e < 8; e++) {
            unsigned h, m, l;
            bsplit3(xv[e], h, m, l);
            ph[e >> 1] |= h << ((e & 1) * 16);
            pm[e >> 1] |= m << ((e & 1) * 16);
            pl[e >> 1] |= l << ((e & 1) * 16);
        }
        int kc = ihi >> 2, quad = ihi & 3, ct = o >> 4, lf = o & 15;
        size_t base = (size_t)(g * 3) * 131072 + (size_t)kc * 16384 + ct * 1024 + quad * 256 + lf * 16;
        *(uint4*)(wsp + base + 0 * 131072) = *(uint4*)ph;
        *(uint4*)(wsp + base + 1 * 131072) = *(uint4*)pm;
        *(uint4*)(wsp + base + 2 * 131072) = *(uint4*)pl;
    } else if (bx < 224) {
        int row  = (bx - 64) * 4 + (tid >> 6);
        int lane = tid & 63;
        float4 v = *(const float4*)(emb + (size_t)row * 256 + lane * 4);
        float s = v.x * v.x + v.y * v.y + v.z * v.z + v.w * v.w;
#pragma unroll
        for (int m = 1; m < 64; m <<= 1) s += __shfl_xor(s, m);
        if (lane == 0) e2w[(row & 1) * Vq + (row >> 1)] = s;
    } else {
        // emb hi-only split (same hi values/layout as validated round-8 esp)
        int t = (bx - 224) * 256 + tid;   // 0..20479
        int g  = t / 10240;
        int r  = t - g * 10240;
        int kc = r / 1280;
        int r2 = r - kc * 1280;
        int ct = r2 >> 6;
        int r3 = r2 & 63;
        int kq = r3 >> 4, l15 = r3 & 15;
        int v  = ct * 16 + l15;
        int k0 = kc * 32 + kq * 8;
        const float* src = emb + ((size_t)v * 2 + g) * 256 + k0;
        float xv[8];
        *(float4*)(xv + 0) = *(const float4*)(src);
        *(float4*)(xv + 4) = *(const float4*)(src + 4);
        unsigned ph[4] = {0,0,0,0};
#pragma unroll
        for (int e = 0; e < 8; e++) {
            unsigned h = rne16(xv[e]);
            ph[e >> 1] |= h << ((e & 1) * 16);
        }
        size_t base = (size_t)g * 327680 + (size_t)kc * 20480
                    + (size_t)((ct * 4 + kq) * 16 + l15) * 16;
        *(uint4*)(esp + base) = *(uint4*)ph;
    }
}

// ---------------- conv GEMM via 6-pass 3-piece bf16 MFMA (round-8 verbatim) -----
__global__ __launch_bounds__(256, 2) void k_convM(const float* __restrict__ x,
    const unsigned char* __restrict__ wsp, float* __restrict__ ze,
    double* __restrict__ pconv)
{
    __shared__ unsigned char lds[73728];   // Bs 48KB | As 24KB
    __shared__ double reds[4], redq[4];
    uint4* Bs = (uint4*)lds;
    uint4* As = (uint4*)(lds + 49152);

    int tid = threadIdx.x, bx = blockIdx.x;
    int mt = bx >> 1, g = bx & 1;
    int m0 = mt * 128;
    int w = tid >> 6, lane = tid & 63;
    int quad = lane >> 4, l15 = lane & 15;
    int arow = tid >> 1, ah = tid & 1;
    int aw = arow >> 5, art = (arow >> 4) & 1, ar = arow & 15;
    const float* xrow = x + (size_t)(m0 + arow) * Cq + g * CGq + ah * 16;
    const unsigned char* wslab = wsp + (size_t)(g * 3) * 131072;

    f32x4v zero4 = {0.f, 0.f, 0.f, 0.f};
    f32x4v acc[2][16];
#pragma unroll
    for (int i = 0; i < 2; i++)
#pragma unroll
        for (int j = 0; j < 16; j++) acc[i][j] = zero4;

    for (int kc = 0; kc < 8; kc++) {
        if (kc) __syncthreads();
#pragma unroll
        for (int j = 0; j < 12; j++) {
            int L = (w * 12 + j) * 1024 + lane * 16;
            int p = L >> 14, r = L & 16383;
            __builtin_amdgcn_global_load_lds(
                (const __attribute__((address_space(1))) void*)(wslab + (size_t)p * 131072 + (size_t)kc * 16384 + r),
                (__attribute__((address_space(3))) void*)(lds + L), 16, 0, 0);
        }
        float xv[16];
        *(float4*)(xv + 0)  = *(const float4*)(xrow + kc * 32 + 0);
        *(float4*)(xv + 4)  = *(const float4*)(xrow + kc * 32 + 4);
        *(float4*)(xv + 8)  = *(const float4*)(xrow + kc * 32 + 8);
        *(float4*)(xv + 12) = *(const float4*)(xrow + kc * 32 + 12);
#pragma unroll
        for (int ii = 0; ii < 2; ii++) {
            unsigned ph[4] = {0,0,0,0}, pm[4] = {0,0,0,0}, pl[4] = {0,0,0,0};
#pragma unroll
            for (int e = 0; e < 8; e++) {
                unsigned h, m, l;
                bsplit3(xv[ii * 8 + e], h, m, l);
                ph[e >> 1] |= h << ((e & 1) * 16);
                pm[e >> 1] |= m << ((e & 1) * 16);
                pl[e >> 1] |= l << ((e & 1) * 16);
            }
            int aq = ah * 2 + ii;
            As[SL(((0 * 4 + aw) * 2 + art) * 4 + aq, ar)] = *(uint4*)ph;
            As[SL(((1 * 4 + aw) * 2 + art) * 4 + aq, ar)] = *(uint4*)pm;
            As[SL(((2 * 4 + aw) * 2 + art) * 4 + aq, ar)] = *(uint4*)pl;
        }
        __syncthreads();
        s16x8 afr[3][2];
#pragma unroll
        for (int p = 0; p < 3; p++)
#pragma unroll
            for (int rt = 0; rt < 2; rt++)
                afr[p][rt] = __builtin_bit_cast(s16x8,
                    As[SL(((p * 4 + w) * 2 + rt) * 4 + quad, l15)]);
#pragma unroll
        for (int ct = 0; ct < 16; ct++) {
            s16x8 b0 = __builtin_bit_cast(s16x8, Bs[0 * 1024 + ct * 64 + quad * 16 + l15]);
            s16x8 b1 = __builtin_bit_cast(s16x8, Bs[1 * 1024 + ct * 64 + quad * 16 + l15]);
            s16x8 b2 = __builtin_bit_cast(s16x8, Bs[2 * 1024 + ct * 64 + quad * 16 + l15]);
#pragma unroll
            for (int rt = 0; rt < 2; rt++) {
                acc[rt][ct] = __builtin_amdgcn_mfma_f32_16x16x32_bf16(afr[0][rt], b0, acc[rt][ct], 0, 0, 0);
                acc[rt][ct] = __builtin_amdgcn_mfma_f32_16x16x32_bf16(afr[1][rt], b0, acc[rt][ct], 0, 0, 0);
                acc[rt][ct] = __builtin_amdgcn_mfma_f32_16x16x32_bf16(afr[2][rt], b0, acc[rt][ct], 0, 0, 0);
                acc[rt][ct] = __builtin_amdgcn_mfma_f32_16x16x32_bf16(afr[0][rt], b1, acc[rt][ct], 0, 0, 0);
                acc[rt][ct] = __builtin_amdgcn_mfma_f32_16x16x32_bf16(afr[1][rt], b1, acc[rt][ct], 0, 0, 0);
                acc[rt][ct] = __builtin_amdgcn_mfma_f32_16x16x32_bf16(afr[0][rt], b2, acc[rt][ct], 0, 0, 0);
            }
        }
    }

    float s = 0.f, q = 0.f;
    float* zb = ze + (size_t)m0 * Cq + g * CGq;
#pragma unroll
    for (int rt = 0; rt < 2; rt++)
#pragma unroll
    for (int ct = 0; ct < 16; ct++)
#pragma unroll
    for (int j = 0; j < 4; j++) {
        float v = acc[rt][ct][j];
        zb[(size_t)(w * 32 + rt * 16 + quad * 4 + j) * Cq + ct * 16 + l15] = v;
        s += v;
        q = __builtin_fmaf(v, v, q);
    }
    double ds = (double)s, dq = (double)q;
#pragma unroll
    for (int m = 1; m < 64; m <<= 1) { ds += __shfl_xor(ds, m); dq += __shfl_xor(dq, m); }
    if (lane == 0) { reds[w] = ds; redq[w] = dq; }
    __syncthreads();
    if (tid == 0) {
        pconv[bx * 2 + 0] = reds[0] + reds[1] + reds[2] + reds[3];
        pconv[bx * 2 + 1] = redq[0] + redq[1] + redq[2] + redq[3];
    }
}

// ---------------- per-(b,g) mean/rstd ----------------
__global__ __launch_bounds__(256) void k_stats(const double* __restrict__ pconv,
                                               float* __restrict__ muw,
                                               float* __restrict__ rsw) {
    int tid = threadIdx.x;
    int bg = tid >> 3, r = tid & 7;
    int b = bg >> 1, g = bg & 1;
    double s = 0.0, q = 0.0;
    for (int j = r; j < 16; j += 8) {
        int pi = (b * 16 + j) * 2 + g;
        s += pconv[pi * 2 + 0];
        q += pconv[pi * 2 + 1];
    }
#pragma unroll
    for (int m = 1; m < 8; m <<= 1) { s += __shfl_xor(s, m); q += __shfl_xor(q, m); }
    if (r == 0) {
        double mu = s / 524288.0;
        double var = q / 524288.0 - mu * mu;
        double rs = 1.0 / sqrt(var + 1e-5);
        muw[bg] = (float)mu;
        rsw[bg] = (float)rs;
    }
}

// --- approx distance: round-8 skeleton, hi-only (1 MFMA pass), fused z2 + loss ---
__global__ __launch_bounds__(256, 2) void k_distA(const unsigned char* __restrict__ esp,
    const float* __restrict__ gw, const float* __restrict__ gb,
    const float* __restrict__ muw, const float* __restrict__ rsw,
    const float* __restrict__ e2w, float* dout,
    unsigned* __restrict__ cntw, unsigned* __restrict__ cnt2w,
    unsigned long long* __restrict__ listq, unsigned* __restrict__ list2,
    unsigned* __restrict__ hist, double* __restrict__ ploss)
{
    __shared__ uint4 Asl[512];             // 8KB swizzled A hi fragments
    __shared__ unsigned char ldsB[20480];  // 20KB pre-split B hi slab
    __shared__ float e2s[Vq];
    __shared__ float z2l[128];
    __shared__ double redp[4];
    uint4* Bsl = (uint4*)ldsB;

    int tid = threadIdx.x, bx = blockIdx.x;
    int mt = bx >> 1, g = bx & 1;
    int m0 = mt * 128;
    int bg = (m0 >> 11) * 2 + g;
    float muf = muw[bg], rsf = rsw[bg];
    int w = tid >> 6, lane = tid & 63;
    int quad = lane >> 4, l15 = lane & 15;

    for (int i = tid; i < Vq; i += 256) e2s[i] = e2w[g * Vq + i];

    int arow = tid >> 1, ah = tid & 1;
    int aw = arow >> 5, art = (arow >> 4) & 1, ar = arow & 15;
    const float* zrow = dout + (size_t)m0 * Cq + g * CGq + (size_t)arow * Cq;
    const unsigned char* eslab = esp + (size_t)g * 327680;

    f32x4v zero4 = {0.f, 0.f, 0.f, 0.f};
    f32x4v acc[2][20];
#pragma unroll
    for (int i = 0; i < 2; i++)
#pragma unroll
        for (int j = 0; j < 20; j++) acc[i][j] = zero4;
    float z2acc = 0.f;   // running sum of zn^2 over this thread's 128 elements

    for (int kc8 = 0; kc8 < 8; kc8++) {
        if (kc8) __syncthreads();
        int k0 = kc8 * 32;
        // ---- B: 20KB global->LDS linear copy of pre-split hi slab ----
#pragma unroll
        for (int j = 0; j < 5; j++) {
            int L = j * 4096 + tid * 16;
            __builtin_amdgcn_global_load_lds(
                (const __attribute__((address_space(1))) void*)(eslab + (size_t)kc8 * 20480 + L),
                (__attribute__((address_space(3))) void*)(ldsB + L), 16, 0, 0);
        }
        // ---- A: normalize + z2 + hi-only pack, swizzled ds_write ----
#pragma unroll
        for (int i2 = 0; i2 < 2; i2++) {
            unsigned hw[4];
#pragma unroll
            for (int ii = 0; ii < 2; ii++) {
                int koff = k0 + ah * 16 + i2 * 8 + ii * 4;
                float4 z  = *(const float4*)(zrow + koff);
                float4 gv = *(const float4*)(gw + g * CGq + koff);
                float4 bvv= *(const float4*)(gb + g * CGq + koff);
                float zn0 = (z.x - muf) * rsf * gv.x + bvv.x;
                float zn1 = (z.y - muf) * rsf * gv.y + bvv.y;
                float zn2 = (z.z - muf) * rsf * gv.z + bvv.z;
                float zn3 = (z.w - muf) * rsf * gv.w + bvv.w;
                z2acc = __builtin_fmaf(zn0, zn0, z2acc);
                z2acc = __builtin_fmaf(zn1, zn1, z2acc);
                z2acc = __builtin_fmaf(zn2, zn2, z2acc);
                z2acc = __builtin_fmaf(zn3, zn3, z2acc);
                hw[ii*2+0] = rne16(zn0) | (rne16(zn1) << 16);
                hw[ii*2+1] = rne16(zn2) | (rne16(zn3) << 16);
            }
            uint4 o1;
            o1.x = hw[0]; o1.y = hw[1]; o1.z = hw[2]; o1.w = hw[3];
            int kq = ah * 2 + i2;
            Asl[SL((aw * 2 + art) * 4 + kq, ar)] = o1;
        }
        __syncthreads();
        s16x8 afr0 = __builtin_bit_cast(s16x8, Asl[SL((w * 2 + 0) * 4 + quad, l15)]);
        s16x8 afr1 = __builtin_bit_cast(s16x8, Asl[SL((w * 2 + 1) * 4 + quad, l15)]);
#pragma unroll
        for (int ct = 0; ct < 20; ct++) {
            s16x8 b = __builtin_bit_cast(s16x8, Bsl[(ct * 4 + quad) * 16 + l15]);
            acc[0][ct] = __builtin_amdgcn_mfma_f32_16x16x32_bf16(afr0, b, acc[0][ct], 0, 0, 0);
            acc[1][ct] = __builtin_amdgcn_mfma_f32_16x16x32_bf16(afr1, b, acc[1][ct], 0, 0, 0);
        }
    }

    // per-row z2: combine the two half-row partials
    {
        float z2pair = z2acc + __shfl_xor(z2acc, 1);
        if (ah == 0) z2l[arow] = z2pair;
    }
    __syncthreads();

    // ---- epilogue: approx argmin + candidate extraction + loss for 1-cand rows --
    double lacc = 0.0;
#pragma unroll
    for (int rt = 0; rt < 2; rt++)
#pragma unroll
    for (int j = 0; j < 4; j++) {
        float m1 = 3.402823466e+38f; int i1 = 0;
#pragma unroll
        for (int ct = 0; ct < 20; ct++) {
            float d2a = e2s[ct * 16 + l15] - 2.0f * acc[rt][ct][j];
            if (d2a < m1) { m1 = d2a; i1 = ct * 16 + l15; }
        }
#pragma unroll
        for (int mm = 1; mm < 16; mm <<= 1) {
            float ov = __shfl_xor(m1, mm);
            int   oi = __shfl_xor(i1, mm);
            if (ov < m1 || (ov == m1 && oi < i1)) { m1 = ov; i1 = oi; }
        }
        float thr = m1 + MARGIN2;
        unsigned mask = 0;
#pragma unroll
        for (int ct = 0; ct < 20; ct++) {
            float d2a = e2s[ct * 16 + l15] - 2.0f * acc[rt][ct][j];
            if (d2a <= thr) mask |= (1u << ct);
        }
        int cnt = __popc(mask);
#pragma unroll
        for (int mm = 1; mm < 16; mm <<= 1) cnt += __shfl_xor(cnt, mm);
        int mrow = m0 + w * 32 + rt * 16 + quad * 4 + j;
        unsigned q = (unsigned)mrow * 2u + (unsigned)g;
        unsigned flag = 0;
        if (cnt > 1) {
            if ((i1 & 15) == l15) mask &= ~(1u << (i1 >> 4));   // best is implicit
            int cl2 = __popc(mask);
            int inc = cl2;
#pragma unroll
            for (int off = 1; off < 16; off <<= 1) {
                int t = __shfl_up(inc, off, 16);
                if (l15 >= off) inc += t;
            }
            int pre = inc - cl2;
            if (cnt <= 5) {
                int pos_ = 0;
                if (l15 == 0) pos_ = (int)atomicAdd(cntw, 1u);
                pos_ = __shfl(pos_, 0, 16);
                if ((unsigned)pos_ < LIST_CAP) {
                    flag = 512u;
                    unsigned long long contrib = 0ull;
                    unsigned mm2 = mask; int k = pre;
                    while (mm2) {
                        int ct2 = __ffs(mm2) - 1; mm2 &= mm2 - 1;
                        contrib |= ((unsigned long long)(unsigned)(ct2 * 16 + l15)) << (20 + 9 * k);
                        k++;
                    }
#pragma unroll
                    for (int mm = 1; mm < 16; mm <<= 1)
                        contrib |= __shfl_xor(contrib, mm);
                    if (l15 == 0)
                        listq[pos_] = (unsigned long long)q
                                    | ((unsigned long long)(unsigned)cnt << 17) | contrib;
                }
            } else {
                if (l15 == 0) {
                    unsigned p2 = atomicAdd(cnt2w, 1u);
                    if (p2 < LIST2_CAP) { list2[p2] = q; flag = 512u; }
                }
            }
        }
        if (l15 == 0) {
            if (flag) {
                dout[IDX_OFF + q] = __uint_as_float((unsigned)i1 | flag);
            } else {
                dout[IDX_OFF + q] = (float)i1;
                atomicAdd(&hist[g * Vq + i1], 1u);
                lacc += (double)z2l[mrow - m0] + (double)m1;
            }
        }
    }
#pragma unroll
    for (int mm = 1; mm < 64; mm <<= 1) lacc += __shfl_xor(lacc, mm);
    if (lane == 0) redp[w] = lacc;
    __syncthreads();
    if (tid == 0) ploss[bx] = redp[0] + redp[1] + redp[2] + redp[3];
}

// -------- exact resolve among <=5 stored candidates + full-scan fallback -------
__global__ __launch_bounds__(256) void k_exF(const float* __restrict__ emb,
    const float* __restrict__ gw, const float* __restrict__ gb,
    const float* __restrict__ muw, const float* __restrict__ rsw,
    const float* __restrict__ e2w, float* dout,
    unsigned* __restrict__ hist, double* __restrict__ ploss2,
    const unsigned long long* __restrict__ listq, const unsigned* __restrict__ cntw,
    double* __restrict__ lossf,
    const unsigned* __restrict__ cnt2w, const unsigned* __restrict__ list2)
{
    int tid = threadIdx.x, lane = tid & 63;
    int gwid = blockIdx.x * 4 + (tid >> 6);
    int cslot = lane >> 2, j = lane & 3;
    unsigned nn = *cntw; if (nn > LIST_CAP) nn = LIST_CAP;
    int n = (int)nn;
    double lacc = 0.0;
    for (int it = gwid; it < n; it += 2048) {
        unsigned long long e = listq[it];
        unsigned q = (unsigned)(e & 0x1FFFFull);
        int cnt = (int)((e >> 17) & 7u);
        int m = (int)(q >> 1), g = (int)(q & 1u);
        int bg = (m >> 11) * 2 + g;
        float muf = muw[bg], rsf = rsw[bg];
        int v = (int)(__float_as_uint(dout[IDX_OFF + q]) & 511u);
        if (cslot >= 1 && cslot < cnt)
            v = (int)((e >> (20 + 9 * (cslot - 1))) & 511ull);
        const float* zb  = dout + (size_t)m * Cq + g * CGq;
        const float* gwb = gw + g * CGq;
        const float* gbb = gb + g * CGq;
        const float* eb  = emb + ((size_t)v * Gq + g) * CGq;
        float z2p = 0.f, dp = 0.f;
        for (int kc = 0; kc < 16; kc++) {
            int k0 = kc * 16 + j * 4;
            float4 z  = *(const float4*)(zb + k0);
            float4 gv = *(const float4*)(gwb + k0);
            float4 bv = *(const float4*)(gbb + k0);
            float4 e4 = *(const float4*)(eb + k0);
            float zn0 = __fadd_rn(__fmul_rn(__fmul_rn(__fsub_rn(z.x, muf), rsf), gv.x), bv.x);
            float zn1 = __fadd_rn(__fmul_rn(__fmul_rn(__fsub_rn(z.y, muf), rsf), gv.y), bv.y);
            float zn2 = __fadd_rn(__fmul_rn(__fmul_rn(__fsub_rn(z.z, muf), rsf), gv.z), bv.z);
            float zn3 = __fadd_rn(__fmul_rn(__fmul_rn(__fsub_rn(z.w, muf), rsf), gv.w), bv.w);
            z2p = __builtin_fmaf(zn0, zn0, z2p);
            z2p = __builtin_fmaf(zn1, zn1, z2p);
            z2p = __builtin_fmaf(zn2, zn2, z2p);
            z2p = __builtin_fmaf(zn3, zn3, z2p);
            dp = __builtin_fmaf(zn0, e4.x, dp);
            dp = __builtin_fmaf(zn1, e4.y, dp);
            dp = __builtin_fmaf(zn2, e4.z, dp);
            dp = __builtin_fmaf(zn3, e4.w, dp);
        }
        z2p += __shfl_xor(z2p, 1); z2p += __shfl_xor(z2p, 2);
        dp  += __shfl_xor(dp, 1);  dp  += __shfl_xor(dp, 2);
        float d2 = __fadd_rn(__fsub_rn(z2p, 2.0f * dp), e2w[g * Vq + v]);
#pragma unroll
        for (int mm = 4; mm < 64; mm <<= 1) {
            float od = __shfl_xor(d2, mm);
            int   ov = __shfl_xor(v, mm);
            if (od < d2 || (od == d2 && ov < v)) { d2 = od; v = ov; }
        }
        if (lane == 0) {
            dout[IDX_OFF + q] = (float)v;
            atomicAdd(&hist[g * Vq + v], 1u);
            lacc += (double)d2;
        }
    }
    if (lane == 0) ploss2[gwid] = lacc;

    // ---- full-scan fallback for >5-candidate rows (expected ~empty) ----
    unsigned nn2 = *cnt2w; if (nn2 > LIST2_CAP) nn2 = LIST2_CAP;
    int n2 = (int)nn2;
    for (int it = gwid; it < n2; it += 2048) {
        int q = (int)list2[it];
        int m = q >> 1, g = q & 1;
        int bg = (m >> 11) * 2 + g;
        float muf = muw[bg], rsf = rsw[bg];
        const float* zb = dout + (size_t)m * Cq + g * CGq;
        int k0 = lane * 4;
        float4 z  = *(const float4*)(zb + k0);
        float4 gv = *(const float4*)(gw + g * CGq + k0);
        float4 bv = *(const float4*)(gb + g * CGq + k0);
        float zn0 = __fadd_rn(__fmul_rn(__fmul_rn(__fsub_rn(z.x, muf), rsf), gv.x), bv.x);
        float zn1 = __fadd_rn(__fmul_rn(__fmul_rn(__fsub_rn(z.y, muf), rsf), gv.y), bv.y);
        float zn2 = __fadd_rn(__fmul_rn(__fmul_rn(__fsub_rn(z.z, muf), rsf), gv.z), bv.z);
        float zn3 = __fadd_rn(__fmul_rn(__fmul_rn(__fsub_rn(z.w, muf), rsf), gv.w), bv.w);
        float s = 0.f;
        for (int kc = 0; kc < 16; kc++) {
            int src = (lane & 3) + kc * 4;
            float a0 = __shfl(zn0, src), a1 = __shfl(zn1, src);
            float a2 = __shfl(zn2, src), a3 = __shfl(zn3, src);
            s = __builtin_fmaf(a0, a0, s);
            s = __builtin_fmaf(a1, a1, s);
            s = __builtin_fmaf(a2, a2, s);
            s = __builtin_fmaf(a3, a3, s);
        }
        s += __shfl_xor(s, 1); s += __shfl_xor(s, 2);
        float z2 = s;
        float m1 = 3.402823466e+38f; int i1 = 0;
        for (int v = 0; v < Vq; v += 2) {
            const float* e0 = emb + ((size_t)v * Gq + g) * CGq + k0;
            float4 ea = *(const float4*)e0;
            float4 eb4 = *(const float4*)(e0 + Gq * CGq);
            float da = zn0 * ea.x;  da = __builtin_fmaf(zn1, ea.y, da);
            da = __builtin_fmaf(zn2, ea.z, da); da = __builtin_fmaf(zn3, ea.w, da);
            float db = zn0 * eb4.x; db = __builtin_fmaf(zn1, eb4.y, db);
            db = __builtin_fmaf(zn2, eb4.z, db); db = __builtin_fmaf(zn3, eb4.w, db);
#pragma unroll
            for (int mm = 1; mm < 64; mm <<= 1) { da += __shfl_xor(da, mm); db += __shfl_xor(db, mm); }
            float d2a = __fadd_rn(__fsub_rn(z2, 2.0f * da), e2w[g * Vq + v]);
            float d2b = __fadd_rn(__fsub_rn(z2, 2.0f * db), e2w[g * Vq + v + 1]);
            if (d2a < m1) { m1 = d2a; i1 = v; }
            if (d2b < m1) { m1 = d2b; i1 = v + 1; }
        }
        if (lane == 0) {
            dout[IDX_OFF + q] = (float)i1;
            atomicAdd(&hist[g * Vq + i1], 1u);
            atomicAdd(lossf, (double)m1);
        }
    }
}

// ---------------- gather ----------------
__global__ __launch_bounds__(256) void k_out(const float* __restrict__ emb, float* dout) {
    size_t u = (size_t)blockIdx.x * 256 + threadIdx.x;
    size_t pos = u * 4;
    int m = (int)(pos >> 9);
    int c = (int)(pos & 511);
    int g = c >> 8, d = c & 255;
    int v = (int)dout[IDX_OFF + (size_t)m * Gq + g];
    float4 o = *(const float4*)(emb + ((size_t)(v * 2 + g)) * 256 + d);
    *(float4*)(dout + pos) = o;
}

// ---------------- finalize loss + perplexity ----------------
__global__ __launch_bounds__(256) void k_final(const double* __restrict__ ploss,
                                               const double* __restrict__ ploss2,
                                               const double* __restrict__ lossf,
                                               const unsigned* __restrict__ hist,
                                               float* dout) {
    __shared__ double redl[4], red0[4], red1[4];
    int tid = threadIdx.x;
    double s = 0.0;
    for (int i = tid; i < 512; i += 256) s += ploss[i];
    for (int i = tid; i < 2048; i += 256) s += ploss2[i];
#pragma unroll
    for (int m = 1; m < 64; m <<= 1) s += __shfl_xor(s, m);
    double e0 = 0.0, e1 = 0.0;
    for (int pid = tid; pid < 640; pid += 256) {
        double p = (double)hist[pid] * (1.0 / 32768.0);
        double t = p * log(p + 1e-7);
        if (pid < 320) e0 += t; else e1 += t;
    }
#pragma unroll
    for (int m = 1; m < 64; m <<= 1) { e0 += __shfl_xor(e0, m); e1 += __shfl_xor(e1, m); }
    int lane = tid & 63, wv_ = tid >> 6;
    if (lane == 0) { redl[wv_] = s; red0[wv_] = e0; red1[wv_] = e1; }
    __syncthreads();
    if (tid == 0) {
        double S  = redl[0] + redl[1] + redl[2] + redl[3] + *lossf;
        double E0 = red0[0] + red0[1] + red0[2] + red0[3];
        double E1 = red1[0] + red1[1] + red1[2] + red1[3];
        dout[LOSS_OFF] = (float)(1.25 * S / 16777216.0);
        dout[PPL_OFF]  = (float)(exp(-E0) + exp(-E1));
    }
}

extern "C" void kernel_launch(void* const* d_in, const int* in_sizes, int n_in,
                              void* d_out, int out_size, void* d_ws, size_t ws_size,
                              hipStream_t stream) {
    const float* x   = (const float*)d_in[0];
    const float* w   = (const float*)d_in[1];
    const float* gw  = (const float*)d_in[2];
    const float* gb  = (const float*)d_in[3];
    const float* emb = (const float*)d_in[4];
    float* dout = (float*)d_out;
    char* ws = (char*)d_ws;
    double* pconv   = (double*)(ws + WS_PCONV);
    double* ploss   = (double*)(ws + WS_PLOSS);
    float* muw      = (float*)(ws + WS_MU);
    float* rsw      = (float*)(ws + WS_RS);
    float* e2w      = (float*)(ws + WS_E2);
    double* lossf   = (double*)(ws + WS_LOSSF);
    unsigned* cntw  = (unsigned*)(ws + WS_CNT);
    unsigned* cnt2w = (unsigned*)(ws + WS_CNT2);
    unsigned* hist  = (unsigned*)(ws + WS_HIST);
    double* ploss2  = (double*)(ws + WS_PL2);
    unsigned* list2 = (unsigned*)(ws + WS_LIST2);
    unsigned char* wsp = (unsigned char*)(ws + WS_WSP);
    unsigned long long* listq = (unsigned long long*)(ws + WS_LISTQ);
    unsigned char* esp = (unsigned char*)(ws + WS_ESP);

    hipMemsetAsync(ws + WS_LOSSF, 0, 2576, stream);   // lossf + cnt + cnt2 + hist
    k_prep<<<304, 256, 0, stream>>>(w, emb, wsp, esp, e2w);
    k_convM<<<512, 256, 0, stream>>>(x, wsp, dout, pconv);    // ze staged in d_out
    k_stats<<<1, 256, 0, stream>>>(pconv, muw, rsw);
    k_distA<<<512, 256, 0, stream>>>(esp, gw, gb, muw, rsw, e2w, dout,
                                     cntw, cnt2w, listq, list2, hist, ploss);
    k_exF<<<512, 256, 0, stream>>>(emb, gw, gb, muw, rsw, e2w, dout, hist, ploss2,
                                   listq, cntw, lossf, cnt2w, list2);
    k_out<<<16384, 256, 0, stream>>>(emb, dout);
    k_final<<<1, 256, 0, stream>>>(ploss, ploss2, lossf, hist, dout);
}

// Round 13
// 165.136 us; speedup vs baseline: 1.2439x; 1.1619x over previous
//
#include <hip/hip_runtime.h>

#define Bq 16
#define Tq 2048
#define Cq 512
#define Gq 2
#define CGq 256
#define Vq 320
#define Mq 32768
#define LOSS_OFF 16777216
#define PPL_OFF  16777217
#define IDX_OFF  16777218

#define MARGIN 1.75e-4f
#define LIST_CAP 16384
#define LIST2_CAP 1024

// workspace byte offsets (round-8 layout; ploss widened to 1024 doubles)
#define WS_PCONV 0          // 512*2 doubles
#define WS_PLOSS 16384      // 1024 doubles -> 24576
#define WS_MU    49152
#define WS_RS    49280
#define WS_E2    49408      // 640 floats -> 51968
#define WS_LOSSF 51968
#define WS_CNT   51976
#define WS_CNT2  51980
#define WS_HIST  51984      // 640 uints -> 54544
#define WS_PL2   54544      // 2048 doubles -> 70928
#define WS_LIST2 70928      // 1024 uints -> 75024
#define WS_WSP   131072     // conv W bf16 pieces: 786432 -> 917504
#define WS_LISTQ 917504     // 16384 u64 -> 1048576
#define WS_ESP   1048576    // emb hi/lo split: 655360

// swizzled A-fragment slot: X = fragment id, r = row 0..15  (2-way max bank alias)
#define SL(X, r) ((X) * 16 + ((r) ^ ((X) & 7)))

typedef short s16x8 __attribute__((ext_vector_type(8)));
typedef float f32x4v __attribute__((ext_vector_type(4)));

// round-to-nearest-even f32 -> (bf16hi bits, bf16lo bits of residual)
__device__ __forceinline__ void bsplit(float x, unsigned &b1, unsigned &b2) {
    unsigned u = __float_as_uint(x);
    unsigned r1 = (u + 0x7fffu + ((u >> 16) & 1u)) & 0xffff0000u;
    b1 = r1 >> 16;
    float d = x - __uint_as_float(r1);
    unsigned u2 = __float_as_uint(d);
    b2 = (u2 + 0x7fffu + ((u2 >> 16) & 1u)) >> 16;
}

// 3-piece split: x = h + m + l
__device__ __forceinline__ void bsplit3(float x, unsigned &h, unsigned &m, unsigned &l) {
    unsigned u = __float_as_uint(x);
    unsigned r1 = (u + 0x7fffu + ((u >> 16) & 1u)) & 0xffff0000u;
    h = r1 >> 16;
    float d1 = x - __uint_as_float(r1);
    unsigned u2 = __float_as_uint(d1);
    unsigned r2 = (u2 + 0x7fffu + ((u2 >> 16) & 1u)) & 0xffff0000u;
    m = r2 >> 16;
    float d2 = d1 - __uint_as_float(r2);
    unsigned u3 = __float_as_uint(d2);
    l = (u3 + 0x7fffu + ((u3 >> 16) & 1u)) >> 16;
}

// ---------------- merged prep: W split (bx<64) | e2 (bx<224) | emb hi/lo split --
__global__ __launch_bounds__(256) void k_prep(const float* __restrict__ w,
                                              const float* __restrict__ emb,
                                              unsigned char* __restrict__ wsp,
                                              unsigned char* __restrict__ esp,
                                              float* __restrict__ e2w) {
    int bx = blockIdx.x, tid = threadIdx.x;
    if (bx < 64) {
        int t = bx * 256 + tid;   // 0..16383
        int g = t >> 13, o = (t >> 5) & 255, ihi = t & 31;
        const float* src = w + ((size_t)(g * 256 + o)) * 256 + ihi * 8;
        float xv[8];
        *(float4*)(xv + 0) = *(const float4*)(src);
        *(float4*)(xv + 4) = *(const float4*)(src + 4);
        unsigned ph[4] = {0,0,0,0}, pm[4] = {0,0,0,0}, pl[4] = {0,0,0,0};
#pragma unroll
        for (int e = 0; e < 8; e++) {
            unsigned h, m, l;
            bsplit3(xv[e], h, m, l);
            ph[e >> 1] |= h << ((e & 1) * 16);
            pm[e >> 1] |= m << ((e & 1) * 16);
            pl[e >> 1] |= l << ((e & 1) * 16);
        }
        int kc = ihi >> 2, quad = ihi & 3, ct = o >> 4, lf = o & 15;
        size_t base = (size_t)(g * 3) * 131072 + (size_t)kc * 16384 + ct * 1024 + quad * 256 + lf * 16;
        *(uint4*)(wsp + base + 0 * 131072) = *(uint4*)ph;
        *(uint4*)(wsp + base + 1 * 131072) = *(uint4*)pm;
        *(uint4*)(wsp + base + 2 * 131072) = *(uint4*)pl;
    } else if (bx < 224) {
        int row  = (bx - 64) * 4 + (tid >> 6);
        int lane = tid & 63;
        float4 v = *(const float4*)(emb + (size_t)row * 256 + lane * 4);
        float s = v.x * v.x + v.y * v.y + v.z * v.z + v.w * v.w;
#pragma unroll
        for (int m = 1; m < 64; m <<= 1) s += __shfl_xor(s, m);
        if (lane == 0) e2w[(row & 1) * Vq + (row >> 1)] = s;
    } else {
        // emb pre-split hi/lo, distA fragment order (round-8 verbatim)
        int t = (bx - 224) * 256 + tid;   // 0..20479
        int g  = t / 10240;
        int r  = t - g * 10240;
        int kc = r / 1280;
        int r2 = r - kc * 1280;
        int ct = r2 >> 6;
        int r3 = r2 & 63;
        int kq = r3 >> 4, l15 = r3 & 15;
        int v  = ct * 16 + l15;
        int k0 = kc * 32 + kq * 8;
        const float* src = emb + ((size_t)v * 2 + g) * 256 + k0;
        float xv[8];
        *(float4*)(xv + 0) = *(const float4*)(src);
        *(float4*)(xv + 4) = *(const float4*)(src + 4);
        unsigned ph[4] = {0,0,0,0}, pl[4] = {0,0,0,0};
#pragma unroll
        for (int e = 0; e < 8; e++) {
            unsigned h, l;
            bsplit(xv[e], h, l);
            ph[e >> 1] |= h << ((e & 1) * 16);
            pl[e >> 1] |= l << ((e & 1) * 16);
        }
        size_t base = (size_t)g * 327680 + (size_t)kc * 20480
                    + (size_t)((ct * 4 + kq) * 16 + l15) * 16;
        *(uint4*)(esp + base) = *(uint4*)ph;
        *(uint4*)(esp + base + 163840) = *(uint4*)pl;
    }
}

// ---------------- conv GEMM via 6-pass 3-piece bf16 MFMA (round-8 verbatim) -----
__global__ __launch_bounds__(256, 2) void k_convM(const float* __restrict__ x,
    const unsigned char* __restrict__ wsp, float* __restrict__ ze,
    double* __restrict__ pconv)
{
    __shared__ unsigned char lds[73728];   // Bs 48KB | As 24KB
    __shared__ double reds[4], redq[4];
    uint4* Bs = (uint4*)lds;
    uint4* As = (uint4*)(lds + 49152);

    int tid = threadIdx.x, bx = blockIdx.x;
    int mt = bx >> 1, g = bx & 1;
    int m0 = mt * 128;
    int w = tid >> 6, lane = tid & 63;
    int quad = lane >> 4, l15 = lane & 15;
    int arow = tid >> 1, ah = tid & 1;
    int aw = arow >> 5, art = (arow >> 4) & 1, ar = arow & 15;
    const float* xrow = x + (size_t)(m0 + arow) * Cq + g * CGq + ah * 16;
    const unsigned char* wslab = wsp + (size_t)(g * 3) * 131072;

    f32x4v zero4 = {0.f, 0.f, 0.f, 0.f};
    f32x4v acc[2][16];
#pragma unroll
    for (int i = 0; i < 2; i++)
#pragma unroll
        for (int j = 0; j < 16; j++) acc[i][j] = zero4;

    for (int kc = 0; kc < 8; kc++) {
        if (kc) __syncthreads();
#pragma unroll
        for (int j = 0; j < 12; j++) {
            int L = (w * 12 + j) * 1024 + lane * 16;
            int p = L >> 14, r = L & 16383;
            __builtin_amdgcn_global_load_lds(
                (const __attribute__((address_space(1))) void*)(wslab + (size_t)p * 131072 + (size_t)kc * 16384 + r),
                (__attribute__((address_space(3))) void*)(lds + L), 16, 0, 0);
        }
        float xv[16];
        *(float4*)(xv + 0)  = *(const float4*)(xrow + kc * 32 + 0);
        *(float4*)(xv + 4)  = *(const float4*)(xrow + kc * 32 + 4);
        *(float4*)(xv + 8)  = *(const float4*)(xrow + kc * 32 + 8);
        *(float4*)(xv + 12) = *(const float4*)(xrow + kc * 32 + 12);
#pragma unroll
        for (int ii = 0; ii < 2; ii++) {
            unsigned ph[4] = {0,0,0,0}, pm[4] = {0,0,0,0}, pl[4] = {0,0,0,0};
#pragma unroll
            for (int e = 0; e < 8; e++) {
                unsigned h, m, l;
                bsplit3(xv[ii * 8 + e], h, m, l);
                ph[e >> 1] |= h << ((e & 1) * 16);
                pm[e >> 1] |= m << ((e & 1) * 16);
                pl[e >> 1] |= l << ((e & 1) * 16);
            }
            int aq = ah * 2 + ii;
            As[SL(((0 * 4 + aw) * 2 + art) * 4 + aq, ar)] = *(uint4*)ph;
            As[SL(((1 * 4 + aw) * 2 + art) * 4 + aq, ar)] = *(uint4*)pm;
            As[SL(((2 * 4 + aw) * 2 + art) * 4 + aq, ar)] = *(uint4*)pl;
        }
        __syncthreads();
        s16x8 afr[3][2];
#pragma unroll
        for (int p = 0; p < 3; p++)
#pragma unroll
            for (int rt = 0; rt < 2; rt++)
                afr[p][rt] = __builtin_bit_cast(s16x8,
                    As[SL(((p * 4 + w) * 2 + rt) * 4 + quad, l15)]);
#pragma unroll
        for (int ct = 0; ct < 16; ct++) {
            s16x8 b0 = __builtin_bit_cast(s16x8, Bs[0 * 1024 + ct * 64 + quad * 16 + l15]);
            s16x8 b1 = __builtin_bit_cast(s16x8, Bs[1 * 1024 + ct * 64 + quad * 16 + l15]);
            s16x8 b2 = __builtin_bit_cast(s16x8, Bs[2 * 1024 + ct * 64 + quad * 16 + l15]);
#pragma unroll
            for (int rt = 0; rt < 2; rt++) {
                acc[rt][ct] = __builtin_amdgcn_mfma_f32_16x16x32_bf16(afr[0][rt], b0, acc[rt][ct], 0, 0, 0);
                acc[rt][ct] = __builtin_amdgcn_mfma_f32_16x16x32_bf16(afr[1][rt], b0, acc[rt][ct], 0, 0, 0);
                acc[rt][ct] = __builtin_amdgcn_mfma_f32_16x16x32_bf16(afr[2][rt], b0, acc[rt][ct], 0, 0, 0);
                acc[rt][ct] = __builtin_amdgcn_mfma_f32_16x16x32_bf16(afr[0][rt], b1, acc[rt][ct], 0, 0, 0);
                acc[rt][ct] = __builtin_amdgcn_mfma_f32_16x16x32_bf16(afr[1][rt], b1, acc[rt][ct], 0, 0, 0);
                acc[rt][ct] = __builtin_amdgcn_mfma_f32_16x16x32_bf16(afr[0][rt], b2, acc[rt][ct], 0, 0, 0);
            }
        }
    }

    float s = 0.f, q = 0.f;
    float* zb = ze + (size_t)m0 * Cq + g * CGq;
#pragma unroll
    for (int rt = 0; rt < 2; rt++)
#pragma unroll
    for (int ct = 0; ct < 16; ct++)
#pragma unroll
    for (int j = 0; j < 4; j++) {
        float v = acc[rt][ct][j];
        zb[(size_t)(w * 32 + rt * 16 + quad * 4 + j) * Cq + ct * 16 + l15] = v;
        s += v;
        q = __builtin_fmaf(v, v, q);
    }
    double ds = (double)s, dq = (double)q;
#pragma unroll
    for (int m = 1; m < 64; m <<= 1) { ds += __shfl_xor(ds, m); dq += __shfl_xor(dq, m); }
    if (lane == 0) { reds[w] = ds; redq[w] = dq; }
    __syncthreads();
    if (tid == 0) {
        pconv[bx * 2 + 0] = reds[0] + reds[1] + reds[2] + reds[3];
        pconv[bx * 2 + 1] = redq[0] + redq[1] + redq[2] + redq[3];
    }
}

// ---------------- per-(b,g) mean/rstd ----------------
__global__ __launch_bounds__(256) void k_stats(const double* __restrict__ pconv,
                                               float* __restrict__ muw,
                                               float* __restrict__ rsw) {
    int tid = threadIdx.x;
    int bg = tid >> 3, r = tid & 7;
    int b = bg >> 1, g = bg & 1;
    double s = 0.0, q = 0.0;
    for (int j = r; j < 16; j += 8) {
        int pi = (b * 16 + j) * 2 + g;
        s += pconv[pi * 2 + 0];
        q += pconv[pi * 2 + 1];
    }
#pragma unroll
    for (int m = 1; m < 8; m <<= 1) { s += __shfl_xor(s, m); q += __shfl_xor(q, m); }
    if (r == 0) {
        double mu = s / 524288.0;
        double var = q / 524288.0 - mu * mu;
        double rs = 1.0 / sqrt(var + 1e-5);
        muw[bg] = (float)mu;
        rsw[bg] = (float)rs;
    }
}

// --- approx distance: 64-row tiles (grid 1024, ~3 blk/CU), round-8 numerics ----
// Per wave: one 16-row tile, 3-pass hi/lo MFMA; fused z2/loss/hist + gather.
__global__ __launch_bounds__(256, 3) void k_distA(const unsigned char* __restrict__ esp,
    const float* __restrict__ gw, const float* __restrict__ gb,
    const float* __restrict__ muw, const float* __restrict__ rsw,
    const float* __restrict__ e2w, const float* __restrict__ emb, float* dout,
    unsigned* __restrict__ cntw, unsigned* __restrict__ cnt2w,
    unsigned long long* __restrict__ listq, unsigned* __restrict__ list2,
    unsigned* __restrict__ hist, double* __restrict__ ploss)
{
    __shared__ uint4 Asl[512];             // 8KB swizzled A hi/lo fragments
    __shared__ unsigned char ldsB[40960];  // 40KB pre-split B hi/lo slabs
    __shared__ float e2s[Vq];
    __shared__ float z2l[64];
    __shared__ unsigned idxl[64];
    __shared__ double redp[4];
    uint4* Bsl = (uint4*)ldsB;

    int tid = threadIdx.x, bx = blockIdx.x;
    int mt = bx >> 1, g = bx & 1;
    int m0 = mt * 64;
    int bg = (m0 >> 11) * 2 + g;
    float muf = muw[bg], rsf = rsw[bg];
    int w = tid >> 6, lane = tid & 63;
    int quad = lane >> 4, l15 = lane & 15;

    for (int i = tid; i < Vq; i += 256) e2s[i] = e2w[g * Vq + i];

    int arow = tid >> 2, akq = tid & 3;        // 64 rows x 4 kq-groups
    int awt = arow >> 4, ar = arow & 15;
    const float* zrow = dout + (size_t)(m0 + arow) * Cq + g * CGq + akq * 8;
    const unsigned char* eslab = esp + (size_t)g * 327680;

    f32x4v zero4 = {0.f, 0.f, 0.f, 0.f};
    f32x4v acc[20];
#pragma unroll
    for (int j = 0; j < 20; j++) acc[j] = zero4;
    float z2acc = 0.f;   // sum of zn^2 over this thread's 64 elements

    for (int kc8 = 0; kc8 < 8; kc8++) {
        if (kc8) __syncthreads();
        int k0 = kc8 * 32;
        // ---- B: 40KB global->LDS linear copy (round-8 verbatim) ----
#pragma unroll
        for (int j = 0; j < 10; j++) {
            int L = j * 4096 + tid * 16;
            int s = (j >= 5) ? 1 : 0;
            __builtin_amdgcn_global_load_lds(
                (const __attribute__((address_space(1))) void*)(eslab + (size_t)s * 143360 + (size_t)kc8 * 20480 + L),
                (__attribute__((address_space(3))) void*)(ldsB + L), 16, 0, 0);
        }
        // ---- A: normalize + z2 + hi/lo split, one fragment per thread ----
        {
            unsigned hw[4], lw[4];
#pragma unroll
            for (int ii = 0; ii < 2; ii++) {
                int koff = k0 + akq * 8 + ii * 4;
                float4 z  = *(const float4*)(zrow + kc8 * 0 + koff - akq * 8 + akq * 8);  // = zrow + koff (zrow already includes akq*8? no)
                (void)z;
                float4 zz = *(const float4*)(dout + (size_t)(m0 + arow) * Cq + g * CGq + koff);
                float4 gv = *(const float4*)(gw + g * CGq + koff);
                float4 bvv= *(const float4*)(gb + g * CGq + koff);
                float zn0 = (zz.x - muf) * rsf * gv.x + bvv.x;
                float zn1 = (zz.y - muf) * rsf * gv.y + bvv.y;
                float zn2 = (zz.z - muf) * rsf * gv.z + bvv.z;
                float zn3 = (zz.w - muf) * rsf * gv.w + bvv.w;
                z2acc = __builtin_fmaf(zn0, zn0, z2acc);
                z2acc = __builtin_fmaf(zn1, zn1, z2acc);
                z2acc = __builtin_fmaf(zn2, zn2, z2acc);
                z2acc = __builtin_fmaf(zn3, zn3, z2acc);
                unsigned h0,l0,h1,l1,h2,l2,h3,l3;
                bsplit(zn0, h0, l0); bsplit(zn1, h1, l1);
                bsplit(zn2, h2, l2); bsplit(zn3, h3, l3);
                hw[ii*2+0] = h0 | (h1 << 16); hw[ii*2+1] = h2 | (h3 << 16);
                lw[ii*2+0] = l0 | (l1 << 16); lw[ii*2+1] = l2 | (l3 << 16);
            }
            uint4 o1, o2;
            o1.x = hw[0]; o1.y = hw[1]; o1.z = hw[2]; o1.w = hw[3];
            o2.x = lw[0]; o2.y = lw[1]; o2.z = lw[2]; o2.w = lw[3];
            Asl[SL((0 * 4 + awt) * 4 + akq, ar)] = o1;
            Asl[SL((1 * 4 + awt) * 4 + akq, ar)] = o2;
        }
        __syncthreads();
        s16x8 ah_ = __builtin_bit_cast(s16x8, Asl[SL((0 * 4 + w) * 4 + quad, l15)]);
        s16x8 al_ = __builtin_bit_cast(s16x8, Asl[SL((1 * 4 + w) * 4 + quad, l15)]);
#pragma unroll
        for (int ct = 0; ct < 20; ct++) {
            s16x8 b0 = __builtin_bit_cast(s16x8, Bsl[(ct * 4 + quad) * 16 + l15]);
            s16x8 b1 = __builtin_bit_cast(s16x8, Bsl[1280 + (ct * 4 + quad) * 16 + l15]);
            acc[ct] = __builtin_amdgcn_mfma_f32_16x16x32_bf16(ah_, b0, acc[ct], 0, 0, 0);
            acc[ct] = __builtin_amdgcn_mfma_f32_16x16x32_bf16(ah_, b1, acc[ct], 0, 0, 0);
            acc[ct] = __builtin_amdgcn_mfma_f32_16x16x32_bf16(al_, b0, acc[ct], 0, 0, 0);
        }
    }

    // per-row z2: combine the 4 kq partials (lanes tid&3)
    {
        float z2p = z2acc + __shfl_xor(z2acc, 1);
        z2p += __shfl_xor(z2p, 2);
        if (akq == 0) z2l[arow] = z2p;
    }
    __syncthreads();

    // ---- epilogue: approx argmin + candidate extraction + loss for 1-cand rows --
    double lacc = 0.0;
#pragma unroll
    for (int j = 0; j < 4; j++) {
        float m1 = 3.402823466e+38f; int i1 = 0;
#pragma unroll
        for (int ct = 0; ct < 20; ct++) {
            float d2a = e2s[ct * 16 + l15] - 2.0f * acc[ct][j];
            if (d2a < m1) { m1 = d2a; i1 = ct * 16 + l15; }
        }
#pragma unroll
        for (int mm = 1; mm < 16; mm <<= 1) {
            float ov = __shfl_xor(m1, mm);
            int   oi = __shfl_xor(i1, mm);
            if (ov < m1 || (ov == m1 && oi < i1)) { m1 = ov; i1 = oi; }
        }
        float thr = m1 + MARGIN;
        unsigned mask = 0;
#pragma unroll
        for (int ct = 0; ct < 20; ct++) {
            float d2a = e2s[ct * 16 + l15] - 2.0f * acc[ct][j];
            if (d2a <= thr) mask |= (1u << ct);
        }
        int cnt = __popc(mask);
#pragma unroll
        for (int mm = 1; mm < 16; mm <<= 1) cnt += __shfl_xor(cnt, mm);
        int mrow = m0 + w * 16 + quad * 4 + j;
        unsigned q = (unsigned)mrow * 2u + (unsigned)g;
        unsigned flag = 0;
        if (cnt > 1) {
            if ((i1 & 15) == l15) mask &= ~(1u << (i1 >> 4));   // best is implicit
            int cl2 = __popc(mask);
            int inc = cl2;
#pragma unroll
            for (int off = 1; off < 16; off <<= 1) {
                int t = __shfl_up(inc, off, 16);
                if (l15 >= off) inc += t;
            }
            int pre = inc - cl2;
            if (cnt <= 5) {
                int pos_ = 0;
                if (l15 == 0) pos_ = (int)atomicAdd(cntw, 1u);
                pos_ = __shfl(pos_, 0, 16);
                if ((unsigned)pos_ < LIST_CAP) {
                    flag = 512u;
                    unsigned long long contrib = 0ull;
                    unsigned mm2 = mask; int k = pre;
                    while (mm2) {
                        int ct2 = __ffs(mm2) - 1; mm2 &= mm2 - 1;
                        contrib |= ((unsigned long long)(unsigned)(ct2 * 16 + l15)) << (20 + 9 * k);
                        k++;
                    }
#pragma unroll
                    for (int mm = 1; mm < 16; mm <<= 1)
                        contrib |= __shfl_xor(contrib, mm);
                    if (l15 == 0)
                        listq[pos_] = (unsigned long long)q
                                    | ((unsigned long long)(unsigned)cnt << 17) | contrib;
                }
            } else {
                if (l15 == 0) {
                    unsigned p2 = atomicAdd(cnt2w, 1u);
                    if (p2 < LIST2_CAP) { list2[p2] = q; flag = 512u; }
                }
            }
        }
        if (l15 == 0) {
            unsigned packed = (unsigned)i1 | flag;
            idxl[mrow - m0] = packed;
            if (flag) {
                dout[IDX_OFF + q] = __uint_as_float(packed);
            } else {
                dout[IDX_OFF + q] = (float)i1;
                atomicAdd(&hist[g * Vq + i1], 1u);
                lacc += (double)z2l[mrow - m0] + (double)m1;
            }
        }
    }
#pragma unroll
    for (int mm = 1; mm < 64; mm <<= 1) lacc += __shfl_xor(lacc, mm);
    if (lane == 0) redp[w] = lacc;
    __syncthreads();
    if (tid == 0) ploss[bx] = redp[0] + redp[1] + redp[2] + redp[3];

    // ---- fused gather for unflagged rows (flagged rows written by k_exF) ----
#pragma unroll
    for (int it = 0; it < 16; it++) {
        int pos = it * 1024 + tid * 4;          // 0..16383 floats
        int row = pos >> 8, d = pos & 255;
        unsigned packed = idxl[row];
        if (!(packed & 512u)) {
            int v = (int)(packed & 511u);
            float4 o = *(const float4*)(emb + ((size_t)(v * 2 + g)) * 256 + d);
            *(float4*)(dout + (size_t)(m0 + row) * Cq + g * CGq + d) = o;
        }
    }
}

// -------- exact resolve among <=5 candidates + full-scan fallback + gather -----
__global__ __launch_bounds__(256) void k_exF(const float* __restrict__ emb,
    const float* __restrict__ gw, const float* __restrict__ gb,
    const float* __restrict__ muw, const float* __restrict__ rsw,
    const float* __restrict__ e2w, float* dout,
    unsigned* __restrict__ hist, double* __restrict__ ploss2,
    const unsigned long long* __restrict__ listq, const unsigned* __restrict__ cntw,
    double* __restrict__ lossf,
    const unsigned* __restrict__ cnt2w, const unsigned* __restrict__ list2)
{
    int tid = threadIdx.x, lane = tid & 63;
    int gwid = blockIdx.x * 4 + (tid >> 6);
    int cslot = lane >> 2, j = lane & 3;
    unsigned nn = *cntw; if (nn > LIST_CAP) nn = LIST_CAP;
    int n = (int)nn;
    double lacc = 0.0;
    for (int it = gwid; it < n; it += 2048) {
        unsigned long long e = listq[it];
        unsigned q = (unsigned)(e & 0x1FFFFull);
        int cnt = (int)((e >> 17) & 7u);
        int m = (int)(q >> 1), g = (int)(q & 1u);
        int bg = (m >> 11) * 2 + g;
        float muf = muw[bg], rsf = rsw[bg];
        int v = (int)(__float_as_uint(dout[IDX_OFF + q]) & 511u);
        if (cslot >= 1 && cslot < cnt)
            v = (int)((e >> (20 + 9 * (cslot - 1))) & 511ull);
        const float* zb  = dout + (size_t)m * Cq + g * CGq;
        const float* gwb = gw + g * CGq;
        const float* gbb = gb + g * CGq;
        const float* eb  = emb + ((size_t)v * Gq + g) * CGq;
        float z2p = 0.f, dp = 0.f;
        for (int kc = 0; kc < 16; kc++) {
            int k0 = kc * 16 + j * 4;
            float4 z  = *(const float4*)(zb + k0);
            float4 gv = *(const float4*)(gwb + k0);
            float4 bv = *(const float4*)(gbb + k0);
            float4 e4 = *(const float4*)(eb + k0);
            float zn0 = __fadd_rn(__fmul_rn(__fmul_rn(__fsub_rn(z.x, muf), rsf), gv.x), bv.x);
            float zn1 = __fadd_rn(__fmul_rn(__fmul_rn(__fsub_rn(z.y, muf), rsf), gv.y), bv.y);
            float zn2 = __fadd_rn(__fmul_rn(__fmul_rn(__fsub_rn(z.z, muf), rsf), gv.z), bv.z);
            float zn3 = __fadd_rn(__fmul_rn(__fmul_rn(__fsub_rn(z.w, muf), rsf), gv.w), bv.w);
            z2p = __builtin_fmaf(zn0, zn0, z2p);
            z2p = __builtin_fmaf(zn1, zn1, z2p);
            z2p = __builtin_fmaf(zn2, zn2, z2p);
            z2p = __builtin_fmaf(zn3, zn3, z2p);
            dp = __builtin_fmaf(zn0, e4.x, dp);
            dp = __builtin_fmaf(zn1, e4.y, dp);
            dp = __builtin_fmaf(zn2, e4.z, dp);
            dp = __builtin_fmaf(zn3, e4.w, dp);
        }
        z2p += __shfl_xor(z2p, 1); z2p += __shfl_xor(z2p, 2);
        dp  += __shfl_xor(dp, 1);  dp  += __shfl_xor(dp, 2);
        float d2 = __fadd_rn(__fsub_rn(z2p, 2.0f * dp), e2w[g * Vq + v]);
#pragma unroll
        for (int mm = 4; mm < 64; mm <<= 1) {
            float od = __shfl_xor(d2, mm);
            int   ov = __shfl_xor(v, mm);
            if (od < d2 || (od == d2 && ov < v)) { d2 = od; v = ov; }
        }
        // all lanes now hold the winning (d2, v)
        if (lane == 0) {
            dout[IDX_OFF + q] = (float)v;
            atomicAdd(&hist[g * Vq + v], 1u);
            lacc += (double)d2;
        }
        // gather this flagged row-half
        {
            float4 o = *(const float4*)(emb + ((size_t)(v * 2 + g)) * 256 + lane * 4);
            *(float4*)(dout + (size_t)m * Cq + g * CGq + lane * 4) = o;
        }
    }
    if (lane == 0) ploss2[gwid] = lacc;

    // ---- full-scan fallback for >5-candidate rows (expected ~empty) ----
    unsigned nn2 = *cnt2w; if (nn2 > LIST2_CAP) nn2 = LIST2_CAP;
    int n2 = (int)nn2;
    for (int it = gwid; it < n2; it += 2048) {
        int q = (int)list2[it];
        int m = q >> 1, g = q & 1;
        int bg = (m >> 11) * 2 + g;
        float muf = muw[bg], rsf = rsw[bg];
        const float* zb = dout + (size_t)m * Cq + g * CGq;
        int k0 = lane * 4;
        float4 z  = *(const float4*)(zb + k0);
        float4 gv = *(const float4*)(gw + g * CGq + k0);
        float4 bv = *(const float4*)(gb + g * CGq + k0);
        float zn0 = __fadd_rn(__fmul_rn(__fmul_rn(__fsub_rn(z.x, muf), rsf), gv.x), bv.x);
        float zn1 = __fadd_rn(__fmul_rn(__fmul_rn(__fsub_rn(z.y, muf), rsf), gv.y), bv.y);
        float zn2 = __fadd_rn(__fmul_rn(__fmul_rn(__fsub_rn(z.z, muf), rsf), gv.z), bv.z);
        float zn3 = __fadd_rn(__fmul_rn(__fmul_rn(__fsub_rn(z.w, muf), rsf), gv.w), bv.w);
        float s = 0.f;
        for (int kc = 0; kc < 16; kc++) {
            int src = (lane & 3) + kc * 4;
            float a0 = __shfl(zn0, src), a1 = __shfl(zn1, src);
            float a2 = __shfl(zn2, src), a3 = __shfl(zn3, src);
            s = __builtin_fmaf(a0, a0, s);
            s = __builtin_fmaf(a1, a1, s);
            s = __builtin_fmaf(a2, a2, s);
            s = __builtin_fmaf(a3, a3, s);
        }
        s += __shfl_xor(s, 1); s += __shfl_xor(s, 2);
        float z2 = s;
        float m1 = 3.402823466e+38f; int i1 = 0;
        for (int v = 0; v < Vq; v += 2) {
            const float* e0 = emb + ((size_t)v * Gq + g) * CGq + k0;
            float4 ea = *(const float4*)e0;
            float4 eb4 = *(const float4*)(e0 + Gq * CGq);
            float da = zn0 * ea.x;  da = __builtin_fmaf(zn1, ea.y, da);
            da = __builtin_fmaf(zn2, ea.z, da); da = __builtin_fmaf(zn3, ea.w, da);
            float db = zn0 * eb4.x; db = __builtin_fmaf(zn1, eb4.y, db);
            db = __builtin_fmaf(zn2, eb4.z, db); db = __builtin_fmaf(zn3, eb4.w, db);
#pragma unroll
            for (int mm = 1; mm < 64; mm <<= 1) { da += __shfl_xor(da, mm); db += __shfl_xor(db, mm); }
            float d2a = __fadd_rn(__fsub_rn(z2, 2.0f * da), e2w[g * Vq + v]);
            float d2b = __fadd_rn(__fsub_rn(z2, 2.0f * db), e2w[g * Vq + v + 1]);
            if (d2a < m1) { m1 = d2a; i1 = v; }
            if (d2b < m1) { m1 = d2b; i1 = v + 1; }
        }
        if (lane == 0) {
            dout[IDX_OFF + q] = (float)i1;
            atomicAdd(&hist[g * Vq + i1], 1u);
            atomicAdd(lossf, (double)m1);
        }
        // all lanes hold identical (m1, i1): gather this row-half
        {
            float4 o = *(const float4*)(emb + ((size_t)(i1 * 2 + g)) * 256 + lane * 4);
            *(float4*)(dout + (size_t)m * Cq + g * CGq + lane * 4) = o;
        }
    }
}

// ---------------- finalize loss + perplexity ----------------
__global__ __launch_bounds__(256) void k_final(const double* __restrict__ ploss,
                                               const double* __restrict__ ploss2,
                                               const double* __restrict__ lossf,
                                               const unsigned* __restrict__ hist,
                                               float* dout) {
    __shared__ double redl[4], red0[4], red1[4];
    int tid = threadIdx.x;
    double s = 0.0;
    for (int i = tid; i < 1024; i += 256) s += ploss[i];
    for (int i = tid; i < 2048; i += 256) s += ploss2[i];
#pragma unroll
    for (int m = 1; m < 64; m <<= 1) s += __shfl_xor(s, m);
    double e0 = 0.0, e1 = 0.0;
    for (int pid = tid; pid < 640; pid += 256) {
        double p = (double)hist[pid] * (1.0 / 32768.0);
        double t = p * log(p + 1e-7);
        if (pid < 320) e0 += t; else e1 += t;
    }
#pragma unroll
    for (int m = 1; m < 64; m <<= 1) { e0 += __shfl_xor(e0, m); e1 += __shfl_xor(e1, m); }
    int lane = tid & 63, wv_ = tid >> 6;
    if (lane == 0) { redl[wv_] = s; red0[wv_] = e0; red1[wv_] = e1; }
    __syncthreads();
    if (tid == 0) {
        double S  = redl[0] + redl[1] + redl[2] + redl[3] + *lossf;
        double E0 = red0[0] + red0[1] + red0[2] + red0[3];
        double E1 = red1[0] + red1[1] + red1[2] + red1[3];
        dout[LOSS_OFF] = (float)(1.25 * S / 16777216.0);
        dout[PPL_OFF]  = (float)(exp(-E0) + exp(-E1));
    }
}

extern "C" void kernel_launch(void* const* d_in, const int* in_sizes, int n_in,
                              void* d_out, int out_size, void* d_ws, size_t ws_size,
                              hipStream_t stream) {
    const float* x   = (const float*)d_in[0];
    const float* w   = (const float*)d_in[1];
    const float* gw  = (const float*)d_in[2];
    const float* gb  = (const float*)d_in[3];
    const float* emb = (const float*)d_in[4];
    float* dout = (float*)d_out;
    char* ws = (char*)d_ws;
    double* pconv   = (double*)(ws + WS_PCONV);
    double* ploss   = (double*)(ws + WS_PLOSS);
    float* muw      = (float*)(ws + WS_MU);
    float* rsw      = (float*)(ws + WS_RS);
    float* e2w      = (float*)(ws + WS_E2);
    double* lossf   = (double*)(ws + WS_LOSSF);
    unsigned* cntw  = (unsigned*)(ws + WS_CNT);
    unsigned* cnt2w = (unsigned*)(ws + WS_CNT2);
    unsigned* hist  = (unsigned*)(ws + WS_HIST);
    double* ploss2  = (double*)(ws + WS_PL2);
    unsigned* list2 = (unsigned*)(ws + WS_LIST2);
    unsigned char* wsp = (unsigned char*)(ws + WS_WSP);
    unsigned long long* listq = (unsigned long long*)(ws + WS_LISTQ);
    unsigned char* esp = (unsigned char*)(ws + WS_ESP);

    hipMemsetAsync(ws + WS_LOSSF, 0, 2576, stream);   // lossf + cnt + cnt2 + hist
    k_prep<<<304, 256, 0, stream>>>(w, emb, wsp, esp, e2w);
    k_convM<<<512, 256, 0, stream>>>(x, wsp, dout, pconv);    // ze staged in d_out
    k_stats<<<1, 256, 0, stream>>>(pconv, muw, rsw);
    k_distA<<<1024, 256, 0, stream>>>(esp, gw, gb, muw, rsw, e2w, emb, dout,
                                      cntw, cnt2w, listq, list2, hist, ploss);
    k_exF<<<512, 256, 0, stream>>>(emb, gw, gb, muw, rsw, e2w, dout, hist, ploss2,
                                   listq, cntw, lossf, cnt2w, list2);
    k_final<<<1, 256, 0, stream>>>(ploss, ploss2, lossf, hist, dout);
}

// Round 14
// 159.372 us; speedup vs baseline: 1.2889x; 1.0362x over previous
//
#include <hip/hip_runtime.h>

#define Bq 16
#define Tq 2048
#define Cq 512
#define Gq 2
#define CGq 256
#define Vq 320
#define Mq 32768
#define LOSS_OFF 16777216
#define PPL_OFF  16777217
#define IDX_OFF  16777218

#define MARGIN 1.75e-4f
#define LIST_CAP 16384
#define LIST2_CAP 1024

// workspace byte offsets
#define WS_PCONV 0          // 512*2 doubles
#define WS_PLOSS 16384      // 512 doubles -> ends 20480
#define WS_MU    49152      // 32 floats
#define WS_RS    49280      // 32 floats
#define WS_E2    49408      // 640 floats -> ends 51968
#define WS_LOSSF 51968      // 1 double
#define WS_CNT   51976      // 1 uint
#define WS_CNT2  51980      // 1 uint
#define WS_HIST  51984      // 640 uints -> ends 54544
#define WS_PL2   54544      // 2048 doubles -> ends 70928
#define WS_LIST2 70928      // 1024 uints -> ends 75024
#define WS_WSP   131072     // conv W bf16 pieces: 786432 -> ends 917504
#define WS_LISTQ 917504     // 16384 u64 -> ends 1048576
#define WS_ESP   1048576    // emb hi/lo split: 655360 -> ends 1703936

// swizzled A-fragment slot: X = fragment id, r = row 0..15  (2-way max bank alias)
#define SL(X, r) ((X) * 16 + ((r) ^ ((X) & 7)))

typedef short s16x8 __attribute__((ext_vector_type(8)));
typedef float f32x4v __attribute__((ext_vector_type(4)));

// round-to-nearest-even f32 -> (bf16hi bits, bf16lo bits of residual)
__device__ __forceinline__ void bsplit(float x, unsigned &b1, unsigned &b2) {
    unsigned u = __float_as_uint(x);
    unsigned r1 = (u + 0x7fffu + ((u >> 16) & 1u)) & 0xffff0000u;
    b1 = r1 >> 16;
    float d = x - __uint_as_float(r1);
    unsigned u2 = __float_as_uint(d);
    b2 = (u2 + 0x7fffu + ((u2 >> 16) & 1u)) >> 16;
}

// 3-piece split: x = h + m + l
__device__ __forceinline__ void bsplit3(float x, unsigned &h, unsigned &m, unsigned &l) {
    unsigned u = __float_as_uint(x);
    unsigned r1 = (u + 0x7fffu + ((u >> 16) & 1u)) & 0xffff0000u;
    h = r1 >> 16;
    float d1 = x - __uint_as_float(r1);
    unsigned u2 = __float_as_uint(d1);
    unsigned r2 = (u2 + 0x7fffu + ((u2 >> 16) & 1u)) & 0xffff0000u;
    m = r2 >> 16;
    float d2 = d1 - __uint_as_float(r2);
    unsigned u3 = __float_as_uint(d2);
    l = (u3 + 0x7fffu + ((u3 >> 16) & 1u)) >> 16;
}

// ---------------- merged prep: W split (bx<64) | e2 (bx<224) | emb split ------
__global__ __launch_bounds__(256) void k_prep(const float* __restrict__ w,
                                              const float* __restrict__ emb,
                                              unsigned char* __restrict__ wsp,
                                              unsigned char* __restrict__ esp,
                                              float* __restrict__ e2w) {
    int bx = blockIdx.x, tid = threadIdx.x;
    if (bx < 64) {
        // ---- W pre-split: 3 bf16 pieces, conv fragment order ----
        int t = bx * 256 + tid;   // 0..16383
        int g = t >> 13, o = (t >> 5) & 255, ihi = t & 31;
        const float* src = w + ((size_t)(g * 256 + o)) * 256 + ihi * 8;
        float xv[8];
        *(float4*)(xv + 0) = *(const float4*)(src);
        *(float4*)(xv + 4) = *(const float4*)(src + 4);
        unsigned ph[4] = {0,0,0,0}, pm[4] = {0,0,0,0}, pl[4] = {0,0,0,0};
#pragma unroll
        for (int e = 0; e < 8; e++) {
            unsigned h, m, l;
            bsplit3(xv[e], h, m, l);
            ph[e >> 1] |= h << ((e & 1) * 16);
            pm[e >> 1] |= m << ((e & 1) * 16);
            pl[e >> 1] |= l << ((e & 1) * 16);
        }
        int kc = ihi >> 2, quad = ihi & 3, ct = o >> 4, lf = o & 15;
        size_t base = (size_t)(g * 3) * 131072 + (size_t)kc * 16384 + ct * 1024 + quad * 256 + lf * 16;
        *(uint4*)(wsp + base + 0 * 131072) = *(uint4*)ph;
        *(uint4*)(wsp + base + 1 * 131072) = *(uint4*)pm;
        *(uint4*)(wsp + base + 2 * 131072) = *(uint4*)pl;
    } else if (bx < 224) {
        // ---- e2[g][v] = sum_d emb[v,g,d]^2 (bit-identical to validated k_e2) ----
        int row  = (bx - 64) * 4 + (tid >> 6);
        int lane = tid & 63;
        float4 v = *(const float4*)(emb + (size_t)row * 256 + lane * 4);
        float s = v.x * v.x + v.y * v.y + v.z * v.z + v.w * v.w;
#pragma unroll
        for (int m = 1; m < 64; m <<= 1) s += __shfl_xor(s, m);
        if (lane == 0) e2w[(row & 1) * Vq + (row >> 1)] = s;
    } else {
        // ---- emb pre-split hi/lo, distA fragment order ----
        int t = (bx - 224) * 256 + tid;   // 0..20479
        int g  = t / 10240;
        int r  = t - g * 10240;
        int kc = r / 1280;
        int r2 = r - kc * 1280;
        int ct = r2 >> 6;
        int r3 = r2 & 63;
        int kq = r3 >> 4, l15 = r3 & 15;
        int v  = ct * 16 + l15;
        int k0 = kc * 32 + kq * 8;
        const float* src = emb + ((size_t)v * 2 + g) * 256 + k0;
        float xv[8];
        *(float4*)(xv + 0) = *(const float4*)(src);
        *(float4*)(xv + 4) = *(const float4*)(src + 4);
        unsigned ph[4] = {0,0,0,0}, pl[4] = {0,0,0,0};
#pragma unroll
        for (int e = 0; e < 8; e++) {
            unsigned h, l;
            bsplit(xv[e], h, l);
            ph[e >> 1] |= h << ((e & 1) * 16);
            pl[e >> 1] |= l << ((e & 1) * 16);
        }
        size_t base = (size_t)g * 327680 + (size_t)kc * 20480
                    + (size_t)((ct * 4 + kq) * 16 + l15) * 16;
        *(uint4*)(esp + base) = *(uint4*)ph;
        *(uint4*)(esp + base + 163840) = *(uint4*)pl;
    }
}

// ---------------- conv GEMM via 6-pass 3-piece bf16 MFMA ----------------
__global__ __launch_bounds__(256, 2) void k_convM(const float* __restrict__ x,
    const unsigned char* __restrict__ wsp, float* __restrict__ ze,
    double* __restrict__ pconv)
{
    __shared__ unsigned char lds[73728];   // Bs 48KB | As 24KB
    __shared__ double reds[4], redq[4];
    uint4* Bs = (uint4*)lds;
    uint4* As = (uint4*)(lds + 49152);

    int tid = threadIdx.x, bx = blockIdx.x;
    int mt = bx >> 1, g = bx & 1;
    int m0 = mt * 128;
    int w = tid >> 6, lane = tid & 63;
    int quad = lane >> 4, l15 = lane & 15;
    int arow = tid >> 1, ah = tid & 1;
    int aw = arow >> 5, art = (arow >> 4) & 1, ar = arow & 15;
    const float* xrow = x + (size_t)(m0 + arow) * Cq + g * CGq + ah * 16;
    const unsigned char* wslab = wsp + (size_t)(g * 3) * 131072;

    f32x4v zero4 = {0.f, 0.f, 0.f, 0.f};
    f32x4v acc[2][16];
#pragma unroll
    for (int i = 0; i < 2; i++)
#pragma unroll
        for (int j = 0; j < 16; j++) acc[i][j] = zero4;

    for (int kc = 0; kc < 8; kc++) {
        if (kc) __syncthreads();
#pragma unroll
        for (int j = 0; j < 12; j++) {
            int L = (w * 12 + j) * 1024 + lane * 16;
            int p = L >> 14, r = L & 16383;
            __builtin_amdgcn_global_load_lds(
                (const __attribute__((address_space(1))) void*)(wslab + (size_t)p * 131072 + (size_t)kc * 16384 + r),
                (__attribute__((address_space(3))) void*)(lds + L), 16, 0, 0);
        }
        float xv[16];
        *(float4*)(xv + 0)  = *(const float4*)(xrow + kc * 32 + 0);
        *(float4*)(xv + 4)  = *(const float4*)(xrow + kc * 32 + 4);
        *(float4*)(xv + 8)  = *(const float4*)(xrow + kc * 32 + 8);
        *(float4*)(xv + 12) = *(const float4*)(xrow + kc * 32 + 12);
#pragma unroll
        for (int ii = 0; ii < 2; ii++) {
            unsigned ph[4] = {0,0,0,0}, pm[4] = {0,0,0,0}, pl[4] = {0,0,0,0};
#pragma unroll
            for (int e = 0; e < 8; e++) {
                unsigned h, m, l;
                bsplit3(xv[ii * 8 + e], h, m, l);
                ph[e >> 1] |= h << ((e & 1) * 16);
                pm[e >> 1] |= m << ((e & 1) * 16);
                pl[e >> 1] |= l << ((e & 1) * 16);
            }
            int aq = ah * 2 + ii;
            As[SL(((0 * 4 + aw) * 2 + art) * 4 + aq, ar)] = *(uint4*)ph;
            As[SL(((1 * 4 + aw) * 2 + art) * 4 + aq, ar)] = *(uint4*)pm;
            As[SL(((2 * 4 + aw) * 2 + art) * 4 + aq, ar)] = *(uint4*)pl;
        }
        __syncthreads();
        s16x8 afr[3][2];
#pragma unroll
        for (int p = 0; p < 3; p++)
#pragma unroll
            for (int rt = 0; rt < 2; rt++)
                afr[p][rt] = __builtin_bit_cast(s16x8,
                    As[SL(((p * 4 + w) * 2 + rt) * 4 + quad, l15)]);
#pragma unroll
        for (int ct = 0; ct < 16; ct++) {
            s16x8 b0 = __builtin_bit_cast(s16x8, Bs[0 * 1024 + ct * 64 + quad * 16 + l15]);
            s16x8 b1 = __builtin_bit_cast(s16x8, Bs[1 * 1024 + ct * 64 + quad * 16 + l15]);
            s16x8 b2 = __builtin_bit_cast(s16x8, Bs[2 * 1024 + ct * 64 + quad * 16 + l15]);
#pragma unroll
            for (int rt = 0; rt < 2; rt++) {
                acc[rt][ct] = __builtin_amdgcn_mfma_f32_16x16x32_bf16(afr[0][rt], b0, acc[rt][ct], 0, 0, 0);
                acc[rt][ct] = __builtin_amdgcn_mfma_f32_16x16x32_bf16(afr[1][rt], b0, acc[rt][ct], 0, 0, 0);
                acc[rt][ct] = __builtin_amdgcn_mfma_f32_16x16x32_bf16(afr[2][rt], b0, acc[rt][ct], 0, 0, 0);
                acc[rt][ct] = __builtin_amdgcn_mfma_f32_16x16x32_bf16(afr[0][rt], b1, acc[rt][ct], 0, 0, 0);
                acc[rt][ct] = __builtin_amdgcn_mfma_f32_16x16x32_bf16(afr[1][rt], b1, acc[rt][ct], 0, 0, 0);
                acc[rt][ct] = __builtin_amdgcn_mfma_f32_16x16x32_bf16(afr[0][rt], b2, acc[rt][ct], 0, 0, 0);
            }
        }
    }

    float s = 0.f, q = 0.f;
    float* zb = ze + (size_t)m0 * Cq + g * CGq;
#pragma unroll
    for (int rt = 0; rt < 2; rt++)
#pragma unroll
    for (int ct = 0; ct < 16; ct++)
#pragma unroll
    for (int j = 0; j < 4; j++) {
        float v = acc[rt][ct][j];
        zb[(size_t)(w * 32 + rt * 16 + quad * 4 + j) * Cq + ct * 16 + l15] = v;
        s += v;
        q = __builtin_fmaf(v, v, q);
    }
    double ds = (double)s, dq = (double)q;
#pragma unroll
    for (int m = 1; m < 64; m <<= 1) { ds += __shfl_xor(ds, m); dq += __shfl_xor(dq, m); }
    if (lane == 0) { reds[w] = ds; redq[w] = dq; }
    __syncthreads();
    if (tid == 0) {
        pconv[bx * 2 + 0] = reds[0] + reds[1] + reds[2] + reds[3];
        pconv[bx * 2 + 1] = redq[0] + redq[1] + redq[2] + redq[3];
    }
}

// ---------------- per-(b,g) mean/rstd ----------------
__global__ __launch_bounds__(256) void k_stats(const double* __restrict__ pconv,
                                               float* __restrict__ muw,
                                               float* __restrict__ rsw) {
    int tid = threadIdx.x;
    int bg = tid >> 3, r = tid & 7;
    int b = bg >> 1, g = bg & 1;
    double s = 0.0, q = 0.0;
    for (int j = r; j < 16; j += 8) {
        int pi = (b * 16 + j) * 2 + g;
        s += pconv[pi * 2 + 0];
        q += pconv[pi * 2 + 1];
    }
#pragma unroll
    for (int m = 1; m < 8; m <<= 1) { s += __shfl_xor(s, m); q += __shfl_xor(q, m); }
    if (r == 0) {
        double mu = s / 524288.0;
        double var = q / 524288.0 - mu * mu;
        double rs = 1.0 / sqrt(var + 1e-5);
        muw[bg] = (float)mu;
        rsw[bg] = (float)rs;
    }
}

// ------ approx distance MFMA + candidate extraction + z2-based loss (no exact) --
__global__ __launch_bounds__(256, 2) void k_distA(const unsigned char* __restrict__ esp,
    const float* __restrict__ gw, const float* __restrict__ gb,
    const float* __restrict__ muw, const float* __restrict__ rsw,
    const float* __restrict__ e2w, float* dout,
    unsigned* __restrict__ cntw, unsigned* __restrict__ cnt2w,
    unsigned long long* __restrict__ listq, unsigned* __restrict__ list2,
    unsigned* __restrict__ hist, double* __restrict__ ploss)
{
    __shared__ uint4 Asl[1024];            // 16KB swizzled A fragments
    __shared__ unsigned char ldsB[40960];  // 40KB pre-split B slabs
    __shared__ float e2s[Vq];
    __shared__ float z2l[128];
    __shared__ double redp[4];
    uint4* Bsl = (uint4*)ldsB;

    int tid = threadIdx.x, bx = blockIdx.x;
    int mt = bx >> 1, g = bx & 1;
    int m0 = mt * 128;
    int bg = (m0 >> 11) * 2 + g;
    float muf = muw[bg], rsf = rsw[bg];
    int w = tid >> 6, lane = tid & 63;
    int quad = lane >> 4, l15 = lane & 15;

    for (int i = tid; i < Vq; i += 256) e2s[i] = e2w[g * Vq + i];

    int arow = tid >> 1, ah = tid & 1;
    int aw = arow >> 5, art = (arow >> 4) & 1, ar = arow & 15;
    const float* zrow = dout + (size_t)m0 * Cq + g * CGq + (size_t)arow * Cq;
    const unsigned char* eslab = esp + (size_t)g * 327680;

    f32x4v zero4 = {0.f, 0.f, 0.f, 0.f};
    f32x4v acc[2][20];
#pragma unroll
    for (int i = 0; i < 2; i++)
#pragma unroll
        for (int j = 0; j < 20; j++) acc[i][j] = zero4;
    float z2acc = 0.f;   // running sum of zn^2 over this thread's 128 elements

    for (int kc8 = 0; kc8 < 8; kc8++) {
        if (kc8) __syncthreads();
        int k0 = kc8 * 32;
#pragma unroll
        for (int j = 0; j < 10; j++) {
            int L = j * 4096 + tid * 16;
            int s = (j >= 5) ? 1 : 0;
            __builtin_amdgcn_global_load_lds(
                (const __attribute__((address_space(1))) void*)(eslab + (size_t)s * 143360 + (size_t)kc8 * 20480 + L),
                (__attribute__((address_space(3))) void*)(ldsB + L), 16, 0, 0);
        }
#pragma unroll
        for (int i2 = 0; i2 < 2; i2++) {
            uint4 o1, o2;
            unsigned hw[4], lw[4];
#pragma unroll
            for (int ii = 0; ii < 2; ii++) {
                int koff = k0 + ah * 16 + i2 * 8 + ii * 4;
                float4 z  = *(const float4*)(zrow + koff);
                float4 gv = *(const float4*)(gw + g * CGq + koff);
                float4 bvv= *(const float4*)(gb + g * CGq + koff);
                float zn0 = (z.x - muf) * rsf * gv.x + bvv.x;
                float zn1 = (z.y - muf) * rsf * gv.y + bvv.y;
                float zn2 = (z.z - muf) * rsf * gv.z + bvv.z;
                float zn3 = (z.w - muf) * rsf * gv.w + bvv.w;
                z2acc = __builtin_fmaf(zn0, zn0, z2acc);
                z2acc = __builtin_fmaf(zn1, zn1, z2acc);
                z2acc = __builtin_fmaf(zn2, zn2, z2acc);
                z2acc = __builtin_fmaf(zn3, zn3, z2acc);
                unsigned h0,l0,h1,l1,h2,l2,h3,l3;
                bsplit(zn0, h0, l0); bsplit(zn1, h1, l1);
                bsplit(zn2, h2, l2); bsplit(zn3, h3, l3);
                hw[ii*2+0] = h0 | (h1 << 16); hw[ii*2+1] = h2 | (h3 << 16);
                lw[ii*2+0] = l0 | (l1 << 16); lw[ii*2+1] = l2 | (l3 << 16);
            }
            o1.x = hw[0]; o1.y = hw[1]; o1.z = hw[2]; o1.w = hw[3];
            o2.x = lw[0]; o2.y = lw[1]; o2.z = lw[2]; o2.w = lw[3];
            int kq = ah * 2 + i2;
            Asl[SL(((0*4 + aw)*2 + art)*4 + kq, ar)] = o1;
            Asl[SL(((1*4 + aw)*2 + art)*4 + kq, ar)] = o2;
        }
        __syncthreads();
        s16x8 afr[2][2];
#pragma unroll
        for (int s = 0; s < 2; s++)
#pragma unroll
            for (int rt = 0; rt < 2; rt++)
                afr[s][rt] = __builtin_bit_cast(s16x8,
                    Asl[SL(((s*4 + w)*2 + rt)*4 + quad, l15)]);
#pragma unroll
        for (int ct = 0; ct < 20; ct++) {
            s16x8 b0 = __builtin_bit_cast(s16x8, Bsl[((0*20 + ct)*4 + quad)*16 + l15]);
            s16x8 b1 = __builtin_bit_cast(s16x8, Bsl[((1*20 + ct)*4 + quad)*16 + l15]);
#pragma unroll
            for (int rt = 0; rt < 2; rt++) {
                acc[rt][ct] = __builtin_amdgcn_mfma_f32_16x16x32_bf16(afr[0][rt], b0, acc[rt][ct], 0, 0, 0);
                acc[rt][ct] = __builtin_amdgcn_mfma_f32_16x16x32_bf16(afr[0][rt], b1, acc[rt][ct], 0, 0, 0);
                acc[rt][ct] = __builtin_amdgcn_mfma_f32_16x16x32_bf16(afr[1][rt], b0, acc[rt][ct], 0, 0, 0);
            }
        }
    }

    // per-row z2: combine the two half-row partials (threads 2r, 2r+1 in same wave)
    {
        float z2pair = z2acc + __shfl_xor(z2acc, 1);
        if (ah == 0) z2l[arow] = z2pair;
    }
    __syncthreads();

    // ---- epilogue: approx argmin + candidate extraction + loss for 1-cand rows --
    double lacc = 0.0;
#pragma unroll
    for (int rt = 0; rt < 2; rt++)
#pragma unroll
    for (int j = 0; j < 4; j++) {
        float m1 = 3.402823466e+38f; int i1 = 0;
#pragma unroll
        for (int ct = 0; ct < 20; ct++) {
            float d2a = e2s[ct * 16 + l15] - 2.0f * acc[rt][ct][j];
            if (d2a < m1) { m1 = d2a; i1 = ct * 16 + l15; }
        }
#pragma unroll
        for (int mm = 1; mm < 16; mm <<= 1) {
            float ov = __shfl_xor(m1, mm);
            int   oi = __shfl_xor(i1, mm);
            if (ov < m1 || (ov == m1 && oi < i1)) { m1 = ov; i1 = oi; }
        }
        float thr = m1 + MARGIN;
        unsigned mask = 0;
#pragma unroll
        for (int ct = 0; ct < 20; ct++) {
            float d2a = e2s[ct * 16 + l15] - 2.0f * acc[rt][ct][j];
            if (d2a <= thr) mask |= (1u << ct);
        }
        int cnt = __popc(mask);
#pragma unroll
        for (int mm = 1; mm < 16; mm <<= 1) cnt += __shfl_xor(cnt, mm);
        int mrow = m0 + w * 32 + rt * 16 + quad * 4 + j;
        unsigned q = (unsigned)mrow * 2u + (unsigned)g;
        unsigned flag = 0;
        if (cnt > 1) {
            if ((i1 & 15) == l15) mask &= ~(1u << (i1 >> 4));   // best is implicit
            int cl2 = __popc(mask);
            int inc = cl2;
#pragma unroll
            for (int off = 1; off < 16; off <<= 1) {
                int t = __shfl_up(inc, off, 16);
                if (l15 >= off) inc += t;
            }
            int pre = inc - cl2;
            if (cnt <= 5) {
                int pos_ = 0;
                if (l15 == 0) pos_ = (int)atomicAdd(cntw, 1u);
                pos_ = __shfl(pos_, 0, 16);
                if ((unsigned)pos_ < LIST_CAP) {
                    flag = 512u;
                    unsigned long long contrib = 0ull;
                    unsigned mm2 = mask; int k = pre;
                    while (mm2) {
                        int ct2 = __ffs(mm2) - 1; mm2 &= mm2 - 1;
                        contrib |= ((unsigned long long)(unsigned)(ct2 * 16 + l15)) << (20 + 9 * k);
                        k++;
                    }
#pragma unroll
                    for (int mm = 1; mm < 16; mm <<= 1)
                        contrib |= __shfl_xor(contrib, mm);
                    if (l15 == 0)
                        listq[pos_] = (unsigned long long)q
                                    | ((unsigned long long)(unsigned)cnt << 17) | contrib;
                }
            } else {
                if (l15 == 0) {
                    unsigned p2 = atomicAdd(cnt2w, 1u);
                    if (p2 < LIST2_CAP) { list2[p2] = q; flag = 512u; }
                }
            }
        }
        if (l15 == 0) {
            if (flag) {
                dout[IDX_OFF + q] = __uint_as_float((unsigned)i1 | flag);
            } else {
                dout[IDX_OFF + q] = (float)i1;
                atomicAdd(&hist[g * Vq + i1], 1u);
                lacc += (double)z2l[mrow - m0] + (double)m1;
            }
        }
    }
#pragma unroll
    for (int mm = 1; mm < 64; mm <<= 1) lacc += __shfl_xor(lacc, mm);
    if (lane == 0) redp[w] = lacc;
    __syncthreads();
    if (tid == 0) ploss[bx] = redp[0] + redp[1] + redp[2] + redp[3];
}

// -------- exact resolve among <=5 stored candidates + full-scan fallback -------
__global__ __launch_bounds__(256) void k_exF(const float* __restrict__ emb,
    const float* __restrict__ gw, const float* __restrict__ gb,
    const float* __restrict__ muw, const float* __restrict__ rsw,
    const float* __restrict__ e2w, float* dout,
    unsigned* __restrict__ hist, double* __restrict__ ploss2,
    const unsigned long long* __restrict__ listq, const unsigned* __restrict__ cntw,
    double* __restrict__ lossf,
    const unsigned* __restrict__ cnt2w, const unsigned* __restrict__ list2)
{
    int tid = threadIdx.x, lane = tid & 63;
    int gwid = blockIdx.x * 4 + (tid >> 6);
    int cslot = lane >> 2, j = lane & 3;
    unsigned nn = *cntw; if (nn > LIST_CAP) nn = LIST_CAP;
    int n = (int)nn;
    double lacc = 0.0;
    for (int it = gwid; it < n; it += 2048) {
        unsigned long long e = listq[it];
        unsigned q = (unsigned)(e & 0x1FFFFull);
        int cnt = (int)((e >> 17) & 7u);
        int m = (int)(q >> 1), g = (int)(q & 1u);
        int bg = (m >> 11) * 2 + g;
        float muf = muw[bg], rsf = rsw[bg];
        int v = (int)(__float_as_uint(dout[IDX_OFF + q]) & 511u);
        if (cslot >= 1 && cslot < cnt)
            v = (int)((e >> (20 + 9 * (cslot - 1))) & 511ull);
        const float* zb  = dout + (size_t)m * Cq + g * CGq;
        const float* gwb = gw + g * CGq;
        const float* gbb = gb + g * CGq;
        const float* eb  = emb + ((size_t)v * Gq + g) * CGq;
        float z2p = 0.f, dp = 0.f;
        for (int kc = 0; kc < 16; kc++) {
            int k0 = kc * 16 + j * 4;
            float4 z  = *(const float4*)(zb + k0);
            float4 gv = *(const float4*)(gwb + k0);
            float4 bv = *(const float4*)(gbb + k0);
            float4 e4 = *(const float4*)(eb + k0);
            float zn0 = __fadd_rn(__fmul_rn(__fmul_rn(__fsub_rn(z.x, muf), rsf), gv.x), bv.x);
            float zn1 = __fadd_rn(__fmul_rn(__fmul_rn(__fsub_rn(z.y, muf), rsf), gv.y), bv.y);
            float zn2 = __fadd_rn(__fmul_rn(__fmul_rn(__fsub_rn(z.z, muf), rsf), gv.z), bv.z);
            float zn3 = __fadd_rn(__fmul_rn(__fmul_rn(__fsub_rn(z.w, muf), rsf), gv.w), bv.w);
            z2p = __builtin_fmaf(zn0, zn0, z2p);
            z2p = __builtin_fmaf(zn1, zn1, z2p);
            z2p = __builtin_fmaf(zn2, zn2, z2p);
            z2p = __builtin_fmaf(zn3, zn3, z2p);
            dp = __builtin_fmaf(zn0, e4.x, dp);
            dp = __builtin_fmaf(zn1, e4.y, dp);
            dp = __builtin_fmaf(zn2, e4.z, dp);
            dp = __builtin_fmaf(zn3, e4.w, dp);
        }
        z2p += __shfl_xor(z2p, 1); z2p += __shfl_xor(z2p, 2);
        dp  += __shfl_xor(dp, 1);  dp  += __shfl_xor(dp, 2);
        float d2 = __fadd_rn(__fsub_rn(z2p, 2.0f * dp), e2w[g * Vq + v]);
#pragma unroll
        for (int mm = 4; mm < 64; mm <<= 1) {
            float od = __shfl_xor(d2, mm);
            int   ov = __shfl_xor(v, mm);
            if (od < d2 || (od == d2 && ov < v)) { d2 = od; v = ov; }
        }
        if (lane == 0) {
            dout[IDX_OFF + q] = (float)v;
            atomicAdd(&hist[g * Vq + v], 1u);
            lacc += (double)d2;
        }
    }
    if (lane == 0) ploss2[gwid] = lacc;

    // ---- full-scan fallback for >5-candidate rows (expected ~empty) ----
    unsigned nn2 = *cnt2w; if (nn2 > LIST2_CAP) nn2 = LIST2_CAP;
    int n2 = (int)nn2;
    for (int it = gwid; it < n2; it += 2048) {
        int q = (int)list2[it];
        int m = q >> 1, g = q & 1;
        int bg = (m >> 11) * 2 + g;
        float muf = muw[bg], rsf = rsw[bg];
        const float* zb = dout + (size_t)m * Cq + g * CGq;
        int k0 = lane * 4;
        float4 z  = *(const float4*)(zb + k0);
        float4 gv = *(const float4*)(gw + g * CGq + k0);
        float4 bv = *(const float4*)(gb + g * CGq + k0);
        float zn0 = __fadd_rn(__fmul_rn(__fmul_rn(__fsub_rn(z.x, muf), rsf), gv.x), bv.x);
        float zn1 = __fadd_rn(__fmul_rn(__fmul_rn(__fsub_rn(z.y, muf), rsf), gv.y), bv.y);
        float zn2 = __fadd_rn(__fmul_rn(__fmul_rn(__fsub_rn(z.z, muf), rsf), gv.z), bv.z);
        float zn3 = __fadd_rn(__fmul_rn(__fmul_rn(__fsub_rn(z.w, muf), rsf), gv.w), bv.w);
        float s = 0.f;
        for (int kc = 0; kc < 16; kc++) {
            int src = (lane & 3) + kc * 4;
            float a0 = __shfl(zn0, src), a1 = __shfl(zn1, src);
            float a2 = __shfl(zn2, src), a3 = __shfl(zn3, src);
            s = __builtin_fmaf(a0, a0, s);
            s = __builtin_fmaf(a1, a1, s);
            s = __builtin_fmaf(a2, a2, s);
            s = __builtin_fmaf(a3, a3, s);
        }
        s += __shfl_xor(s, 1); s += __shfl_xor(s, 2);
        float z2 = s;
        float m1 = 3.402823466e+38f; int i1 = 0;
        for (int v = 0; v < Vq; v += 2) {
            const float* e0 = emb + ((size_t)v * Gq + g) * CGq + k0;
            float4 ea = *(const float4*)e0;
            float4 eb4 = *(const float4*)(e0 + Gq * CGq);
            float da = zn0 * ea.x;  da = __builtin_fmaf(zn1, ea.y, da);
            da = __builtin_fmaf(zn2, ea.z, da); da = __builtin_fmaf(zn3, ea.w, da);
            float db = zn0 * eb4.x; db = __builtin_fmaf(zn1, eb4.y, db);
            db = __builtin_fmaf(zn2, eb4.z, db); db = __builtin_fmaf(zn3, eb4.w, db);
#pragma unroll
            for (int mm = 1; mm < 64; mm <<= 1) { da += __shfl_xor(da, mm); db += __shfl_xor(db, mm); }
            float d2a = __fadd_rn(__fsub_rn(z2, 2.0f * da), e2w[g * Vq + v]);
            float d2b = __fadd_rn(__fsub_rn(z2, 2.0f * db), e2w[g * Vq + v + 1]);
            if (d2a < m1) { m1 = d2a; i1 = v; }
            if (d2b < m1) { m1 = d2b; i1 = v + 1; }
        }
        if (lane == 0) {
            dout[IDX_OFF + q] = (float)i1;
            atomicAdd(&hist[g * Vq + i1], 1u);
            atomicAdd(lossf, (double)m1);
        }
    }
}

// ---------------- gather ----------------
__global__ __launch_bounds__(256) void k_out(const float* __restrict__ emb, float* dout) {
    size_t u = (size_t)blockIdx.x * 256 + threadIdx.x;
    size_t pos = u * 4;
    int m = (int)(pos >> 9);
    int c = (int)(pos & 511);
    int g = c >> 8, d = c & 255;
    int v = (int)dout[IDX_OFF + (size_t)m * Gq + g];
    float4 o = *(const float4*)(emb + ((size_t)(v * 2 + g)) * 256 + d);
    *(float4*)(dout + pos) = o;
}

// ---------------- finalize loss + perplexity ----------------
__global__ __launch_bounds__(256) void k_final(const double* __restrict__ ploss,
                                               const double* __restrict__ ploss2,
                                               const double* __restrict__ lossf,
                                               const unsigned* __restrict__ hist,
                                               float* dout) {
    __shared__ double redl[4], red0[4], red1[4];
    int tid = threadIdx.x;
    double s = 0.0;
    for (int i = tid; i < 512; i += 256) s += ploss[i];
    for (int i = tid; i < 2048; i += 256) s += ploss2[i];
#pragma unroll
    for (int m = 1; m < 64; m <<= 1) s += __shfl_xor(s, m);
    double e0 = 0.0, e1 = 0.0;
    for (int pid = tid; pid < 640; pid += 256) {
        double p = (double)hist[pid] * (1.0 / 32768.0);
        double t = p * log(p + 1e-7);
        if (pid < 320) e0 += t; else e1 += t;
    }
#pragma unroll
    for (int m = 1; m < 64; m <<= 1) { e0 += __shfl_xor(e0, m); e1 += __shfl_xor(e1, m); }
    int lane = tid & 63, wv_ = tid >> 6;
    if (lane == 0) { redl[wv_] = s; red0[wv_] = e0; red1[wv_] = e1; }
    __syncthreads();
    if (tid == 0) {
        double S  = redl[0] + redl[1] + redl[2] + redl[3] + *lossf;
        double E0 = red0[0] + red0[1] + red0[2] + red0[3];
        double E1 = red1[0] + red1[1] + red1[2] + red1[3];
        dout[LOSS_OFF] = (float)(1.25 * S / 16777216.0);
        dout[PPL_OFF]  = (float)(exp(-E0) + exp(-E1));
    }
}

extern "C" void kernel_launch(void* const* d_in, const int* in_sizes, int n_in,
                              void* d_out, int out_size, void* d_ws, size_t ws_size,
                              hipStream_t stream) {
    const float* x   = (const float*)d_in[0];
    const float* w   = (const float*)d_in[1];
    const float* gw  = (const float*)d_in[2];
    const float* gb  = (const float*)d_in[3];
    const float* emb = (const float*)d_in[4];
    float* dout = (float*)d_out;
    char* ws = (char*)d_ws;
    double* pconv   = (double*)(ws + WS_PCONV);
    double* ploss   = (double*)(ws + WS_PLOSS);
    float* muw      = (float*)(ws + WS_MU);
    float* rsw      = (float*)(ws + WS_RS);
    float* e2w      = (float*)(ws + WS_E2);
    double* lossf   = (double*)(ws + WS_LOSSF);
    unsigned* cntw  = (unsigned*)(ws + WS_CNT);
    unsigned* cnt2w = (unsigned*)(ws + WS_CNT2);
    unsigned* hist  = (unsigned*)(ws + WS_HIST);
    double* ploss2  = (double*)(ws + WS_PL2);
    unsigned* list2 = (unsigned*)(ws + WS_LIST2);
    unsigned char* wsp = (unsigned char*)(ws + WS_WSP);
    unsigned long long* listq = (unsigned long long*)(ws + WS_LISTQ);
    unsigned char* esp = (unsigned char*)(ws + WS_ESP);

    hipMemsetAsync(ws + WS_LOSSF, 0, 2576, stream);   // lossf + cnt + cnt2 + hist
    k_prep<<<304, 256, 0, stream>>>(w, emb, wsp, esp, e2w);
    k_convM<<<512, 256, 0, stream>>>(x, wsp, dout, pconv);    // ze staged in d_out
    k_stats<<<1, 256, 0, stream>>>(pconv, muw, rsw);
    k_distA<<<512, 256, 0, stream>>>(esp, gw, gb, muw, rsw, e2w, dout,
                                     cntw, cnt2w, listq, list2, hist, ploss);
    k_exF<<<512, 256, 0, stream>>>(emb, gw, gb, muw, rsw, e2w, dout, hist, ploss2,
                                   listq, cntw, lossf, cnt2w, list2);
    k_out<<<16384, 256, 0, stream>>>(emb, dout);
    k_final<<<1, 256, 0, stream>>>(ploss, ploss2, lossf, hist, dout);
}

// Round 15
// 156.388 us; speedup vs baseline: 1.3135x; 1.0191x over previous
//
#include <hip/hip_runtime.h>

#define Bq 16
#define Tq 2048
#define Cq 512
#define Gq 2
#define CGq 256
#define Vq 320
#define Mq 32768
#define LOSS_OFF 16777216
#define PPL_OFF  16777217
#define IDX_OFF  16777218

#define MARGIN 1.75e-4f
#define LIST_CAP 16384
#define LIST2_CAP 1024

// workspace byte offsets
#define WS_PCONV 0          // 512*2 doubles
#define WS_PLOSS 16384      // 512 doubles -> ends 20480
#define WS_MU    49152      // 32 floats
#define WS_RS    49280      // 32 floats
#define WS_E2    49408      // 640 floats -> ends 51968
#define WS_LOSSF 51968      // 1 double
#define WS_CNT   51976      // 1 uint
#define WS_CNT2  51980      // 1 uint
#define WS_HIST  51984      // 640 uints -> ends 54544
#define WS_PL2   54544      // 2048 doubles -> ends 70928
#define WS_LIST2 70928      // 1024 uints -> ends 75024
#define WS_WSP   131072     // conv W bf16 pieces: 786432 -> ends 917504
#define WS_LISTQ 917504     // 16384 u64 -> ends 1048576
#define WS_ESP   1048576    // emb hi/lo split: 655360 -> ends 1703936

// swizzled A-fragment slot: X = fragment id, r = row 0..15  (2-way max bank alias)
#define SL(X, r) ((X) * 16 + ((r) ^ ((X) & 7)))

typedef short s16x8 __attribute__((ext_vector_type(8)));
typedef float f32x4v __attribute__((ext_vector_type(4)));

// round-to-nearest-even f32 -> (bf16hi bits, bf16lo bits of residual)
__device__ __forceinline__ void bsplit(float x, unsigned &b1, unsigned &b2) {
    unsigned u = __float_as_uint(x);
    unsigned r1 = (u + 0x7fffu + ((u >> 16) & 1u)) & 0xffff0000u;
    b1 = r1 >> 16;
    float d = x - __uint_as_float(r1);
    unsigned u2 = __float_as_uint(d);
    b2 = (u2 + 0x7fffu + ((u2 >> 16) & 1u)) >> 16;
}

// 3-piece split: x = h + m + l
__device__ __forceinline__ void bsplit3(float x, unsigned &h, unsigned &m, unsigned &l) {
    unsigned u = __float_as_uint(x);
    unsigned r1 = (u + 0x7fffu + ((u >> 16) & 1u)) & 0xffff0000u;
    h = r1 >> 16;
    float d1 = x - __uint_as_float(r1);
    unsigned u2 = __float_as_uint(d1);
    unsigned r2 = (u2 + 0x7fffu + ((u2 >> 16) & 1u)) & 0xffff0000u;
    m = r2 >> 16;
    float d2 = d1 - __uint_as_float(r2);
    unsigned u3 = __float_as_uint(d2);
    l = (u3 + 0x7fffu + ((u3 >> 16) & 1u)) >> 16;
}

// ---------------- merged prep: W split (bx<64) | e2 (bx<224) | emb split ------
__global__ __launch_bounds__(256) void k_prep(const float* __restrict__ w,
                                              const float* __restrict__ emb,
                                              unsigned char* __restrict__ wsp,
                                              unsigned char* __restrict__ esp,
                                              float* __restrict__ e2w) {
    int bx = blockIdx.x, tid = threadIdx.x;
    if (bx < 64) {
        int t = bx * 256 + tid;   // 0..16383
        int g = t >> 13, o = (t >> 5) & 255, ihi = t & 31;
        const float* src = w + ((size_t)(g * 256 + o)) * 256 + ihi * 8;
        float xv[8];
        *(float4*)(xv + 0) = *(const float4*)(src);
        *(float4*)(xv + 4) = *(const float4*)(src + 4);
        unsigned ph[4] = {0,0,0,0}, pm[4] = {0,0,0,0}, pl[4] = {0,0,0,0};
#pragma unroll
        for (int e = 0; e < 8; e++) {
            unsigned h, m, l;
            bsplit3(xv[e], h, m, l);
            ph[e >> 1] |= h << ((e & 1) * 16);
            pm[e >> 1] |= m << ((e & 1) * 16);
            pl[e >> 1] |= l << ((e & 1) * 16);
        }
        int kc = ihi >> 2, quad = ihi & 3, ct = o >> 4, lf = o & 15;
        size_t base = (size_t)(g * 3) * 131072 + (size_t)kc * 16384 + ct * 1024 + quad * 256 + lf * 16;
        *(uint4*)(wsp + base + 0 * 131072) = *(uint4*)ph;
        *(uint4*)(wsp + base + 1 * 131072) = *(uint4*)pm;
        *(uint4*)(wsp + base + 2 * 131072) = *(uint4*)pl;
    } else if (bx < 224) {
        int row  = (bx - 64) * 4 + (tid >> 6);
        int lane = tid & 63;
        float4 v = *(const float4*)(emb + (size_t)row * 256 + lane * 4);
        float s = v.x * v.x + v.y * v.y + v.z * v.z + v.w * v.w;
#pragma unroll
        for (int m = 1; m < 64; m <<= 1) s += __shfl_xor(s, m);
        if (lane == 0) e2w[(row & 1) * Vq + (row >> 1)] = s;
    } else {
        int t = (bx - 224) * 256 + tid;   // 0..20479
        int g  = t / 10240;
        int r  = t - g * 10240;
        int kc = r / 1280;
        int r2 = r - kc * 1280;
        int ct = r2 >> 6;
        int r3 = r2 & 63;
        int kq = r3 >> 4, l15 = r3 & 15;
        int v  = ct * 16 + l15;
        int k0 = kc * 32 + kq * 8;
        const float* src = emb + ((size_t)v * 2 + g) * 256 + k0;
        float xv[8];
        *(float4*)(xv + 0) = *(const float4*)(src);
        *(float4*)(xv + 4) = *(const float4*)(src + 4);
        unsigned ph[4] = {0,0,0,0}, pl[4] = {0,0,0,0};
#pragma unroll
        for (int e = 0; e < 8; e++) {
            unsigned h, l;
            bsplit(xv[e], h, l);
            ph[e >> 1] |= h << ((e & 1) * 16);
            pl[e >> 1] |= l << ((e & 1) * 16);
        }
        size_t base = (size_t)g * 327680 + (size_t)kc * 20480
                    + (size_t)((ct * 4 + kq) * 16 + l15) * 16;
        *(uint4*)(esp + base) = *(uint4*)ph;
        *(uint4*)(esp + base + 163840) = *(uint4*)pl;
    }
}

// ---------------- conv GEMM via 6-pass 3-piece bf16 MFMA ----------------
__global__ __launch_bounds__(256, 2) void k_convM(const float* __restrict__ x,
    const unsigned char* __restrict__ wsp, float* __restrict__ ze,
    double* __restrict__ pconv)
{
    __shared__ unsigned char lds[73728];   // Bs 48KB | As 24KB
    __shared__ double reds[4], redq[4];
    uint4* Bs = (uint4*)lds;
    uint4* As = (uint4*)(lds + 49152);

    int tid = threadIdx.x, bx = blockIdx.x;
    int mt = bx >> 1, g = bx & 1;
    int m0 = mt * 128;
    int w = tid >> 6, lane = tid & 63;
    int quad = lane >> 4, l15 = lane & 15;
    int arow = tid >> 1, ah = tid & 1;
    int aw = arow >> 5, art = (arow >> 4) & 1, ar = arow & 15;
    const float* xrow = x + (size_t)(m0 + arow) * Cq + g * CGq + ah * 16;
    const unsigned char* wslab = wsp + (size_t)(g * 3) * 131072;

    f32x4v zero4 = {0.f, 0.f, 0.f, 0.f};
    f32x4v acc[2][16];
#pragma unroll
    for (int i = 0; i < 2; i++)
#pragma unroll
        for (int j = 0; j < 16; j++) acc[i][j] = zero4;

    for (int kc = 0; kc < 8; kc++) {
        if (kc) __syncthreads();
#pragma unroll
        for (int j = 0; j < 12; j++) {
            int L = (w * 12 + j) * 1024 + lane * 16;
            int p = L >> 14, r = L & 16383;
            __builtin_amdgcn_global_load_lds(
                (const __attribute__((address_space(1))) void*)(wslab + (size_t)p * 131072 + (size_t)kc * 16384 + r),
                (__attribute__((address_space(3))) void*)(lds + L), 16, 0, 0);
        }
        float xv[16];
        *(float4*)(xv + 0)  = *(const float4*)(xrow + kc * 32 + 0);
        *(float4*)(xv + 4)  = *(const float4*)(xrow + kc * 32 + 4);
        *(float4*)(xv + 8)  = *(const float4*)(xrow + kc * 32 + 8);
        *(float4*)(xv + 12) = *(const float4*)(xrow + kc * 32 + 12);
#pragma unroll
        for (int ii = 0; ii < 2; ii++) {
            unsigned ph[4] = {0,0,0,0}, pm[4] = {0,0,0,0}, pl[4] = {0,0,0,0};
#pragma unroll
            for (int e = 0; e < 8; e++) {
                unsigned h, m, l;
                bsplit3(xv[ii * 8 + e], h, m, l);
                ph[e >> 1] |= h << ((e & 1) * 16);
                pm[e >> 1] |= m << ((e & 1) * 16);
                pl[e >> 1] |= l << ((e & 1) * 16);
            }
            int aq = ah * 2 + ii;
            As[SL(((0 * 4 + aw) * 2 + art) * 4 + aq, ar)] = *(uint4*)ph;
            As[SL(((1 * 4 + aw) * 2 + art) * 4 + aq, ar)] = *(uint4*)pm;
            As[SL(((2 * 4 + aw) * 2 + art) * 4 + aq, ar)] = *(uint4*)pl;
        }
        __syncthreads();
        s16x8 afr[3][2];
#pragma unroll
        for (int p = 0; p < 3; p++)
#pragma unroll
            for (int rt = 0; rt < 2; rt++)
                afr[p][rt] = __builtin_bit_cast(s16x8,
                    As[SL(((p * 4 + w) * 2 + rt) * 4 + quad, l15)]);
#pragma unroll
        for (int ct = 0; ct < 16; ct++) {
            s16x8 b0 = __builtin_bit_cast(s16x8, Bs[0 * 1024 + ct * 64 + quad * 16 + l15]);
            s16x8 b1 = __builtin_bit_cast(s16x8, Bs[1 * 1024 + ct * 64 + quad * 16 + l15]);
            s16x8 b2 = __builtin_bit_cast(s16x8, Bs[2 * 1024 + ct * 64 + quad * 16 + l15]);
#pragma unroll
            for (int rt = 0; rt < 2; rt++) {
                acc[rt][ct] = __builtin_amdgcn_mfma_f32_16x16x32_bf16(afr[0][rt], b0, acc[rt][ct], 0, 0, 0);
                acc[rt][ct] = __builtin_amdgcn_mfma_f32_16x16x32_bf16(afr[1][rt], b0, acc[rt][ct], 0, 0, 0);
                acc[rt][ct] = __builtin_amdgcn_mfma_f32_16x16x32_bf16(afr[2][rt], b0, acc[rt][ct], 0, 0, 0);
                acc[rt][ct] = __builtin_amdgcn_mfma_f32_16x16x32_bf16(afr[0][rt], b1, acc[rt][ct], 0, 0, 0);
                acc[rt][ct] = __builtin_amdgcn_mfma_f32_16x16x32_bf16(afr[1][rt], b1, acc[rt][ct], 0, 0, 0);
                acc[rt][ct] = __builtin_amdgcn_mfma_f32_16x16x32_bf16(afr[0][rt], b2, acc[rt][ct], 0, 0, 0);
            }
        }
    }

    float s = 0.f, q = 0.f;
    float* zb = ze + (size_t)m0 * Cq + g * CGq;
#pragma unroll
    for (int rt = 0; rt < 2; rt++)
#pragma unroll
    for (int ct = 0; ct < 16; ct++)
#pragma unroll
    for (int j = 0; j < 4; j++) {
        float v = acc[rt][ct][j];
        zb[(size_t)(w * 32 + rt * 16 + quad * 4 + j) * Cq + ct * 16 + l15] = v;
        s += v;
        q = __builtin_fmaf(v, v, q);
    }
    double ds = (double)s, dq = (double)q;
#pragma unroll
    for (int m = 1; m < 64; m <<= 1) { ds += __shfl_xor(ds, m); dq += __shfl_xor(dq, m); }
    if (lane == 0) { reds[w] = ds; redq[w] = dq; }
    __syncthreads();
    if (tid == 0) {
        pconv[bx * 2 + 0] = reds[0] + reds[1] + reds[2] + reds[3];
        pconv[bx * 2 + 1] = redq[0] + redq[1] + redq[2] + redq[3];
    }
}

// ---------------- per-(b,g) mean/rstd ----------------
__global__ __launch_bounds__(256) void k_stats(const double* __restrict__ pconv,
                                               float* __restrict__ muw,
                                               float* __restrict__ rsw) {
    int tid = threadIdx.x;
    int bg = tid >> 3, r = tid & 7;
    int b = bg >> 1, g = bg & 1;
    double s = 0.0, q = 0.0;
    for (int j = r; j < 16; j += 8) {
        int pi = (b * 16 + j) * 2 + g;
        s += pconv[pi * 2 + 0];
        q += pconv[pi * 2 + 1];
    }
#pragma unroll
    for (int m = 1; m < 8; m <<= 1) { s += __shfl_xor(s, m); q += __shfl_xor(q, m); }
    if (r == 0) {
        double mu = s / 524288.0;
        double var = q / 524288.0 - mu * mu;
        double rs = 1.0 / sqrt(var + 1e-5);
        muw[bg] = (float)mu;
        rsw[bg] = (float)rs;
    }
}

// --- approx distance MFMA + extraction + z2 loss + FUSED gather (unflagged) ----
__global__ __launch_bounds__(256, 2) void k_distA(const unsigned char* __restrict__ esp,
    const float* __restrict__ gw, const float* __restrict__ gb,
    const float* __restrict__ muw, const float* __restrict__ rsw,
    const float* __restrict__ e2w, const float* __restrict__ emb, float* dout,
    unsigned* __restrict__ cntw, unsigned* __restrict__ cnt2w,
    unsigned long long* __restrict__ listq, unsigned* __restrict__ list2,
    unsigned* __restrict__ hist, double* __restrict__ ploss)
{
    __shared__ uint4 Asl[1024];            // 16KB swizzled A fragments
    __shared__ unsigned char ldsB[40960];  // 40KB pre-split B slabs
    __shared__ float e2s[Vq];
    __shared__ float z2l[128];
    __shared__ unsigned idxl[128];
    __shared__ double redp[4];
    uint4* Bsl = (uint4*)ldsB;

    int tid = threadIdx.x, bx = blockIdx.x;
    int mt = bx >> 1, g = bx & 1;
    int m0 = mt * 128;
    int bg = (m0 >> 11) * 2 + g;
    float muf = muw[bg], rsf = rsw[bg];
    int w = tid >> 6, lane = tid & 63;
    int quad = lane >> 4, l15 = lane & 15;

    for (int i = tid; i < Vq; i += 256) e2s[i] = e2w[g * Vq + i];

    int arow = tid >> 1, ah = tid & 1;
    int aw = arow >> 5, art = (arow >> 4) & 1, ar = arow & 15;
    const float* zrow = dout + (size_t)m0 * Cq + g * CGq + (size_t)arow * Cq;
    const unsigned char* eslab = esp + (size_t)g * 327680;

    f32x4v zero4 = {0.f, 0.f, 0.f, 0.f};
    f32x4v acc[2][20];
#pragma unroll
    for (int i = 0; i < 2; i++)
#pragma unroll
        for (int j = 0; j < 20; j++) acc[i][j] = zero4;
    float z2acc = 0.f;   // running sum of zn^2 over this thread's 128 elements

    for (int kc8 = 0; kc8 < 8; kc8++) {
        if (kc8) __syncthreads();
        int k0 = kc8 * 32;
#pragma unroll
        for (int j = 0; j < 10; j++) {
            int L = j * 4096 + tid * 16;
            int s = (j >= 5) ? 1 : 0;
            __builtin_amdgcn_global_load_lds(
                (const __attribute__((address_space(1))) void*)(eslab + (size_t)s * 143360 + (size_t)kc8 * 20480 + L),
                (__attribute__((address_space(3))) void*)(ldsB + L), 16, 0, 0);
        }
#pragma unroll
        for (int i2 = 0; i2 < 2; i2++) {
            uint4 o1, o2;
            unsigned hw[4], lw[4];
#pragma unroll
            for (int ii = 0; ii < 2; ii++) {
                int koff = k0 + ah * 16 + i2 * 8 + ii * 4;
                float4 z  = *(const float4*)(zrow + koff);
                float4 gv = *(const float4*)(gw + g * CGq + koff);
                float4 bvv= *(const float4*)(gb + g * CGq + koff);
                float zn0 = (z.x - muf) * rsf * gv.x + bvv.x;
                float zn1 = (z.y - muf) * rsf * gv.y + bvv.y;
                float zn2 = (z.z - muf) * rsf * gv.z + bvv.z;
                float zn3 = (z.w - muf) * rsf * gv.w + bvv.w;
                z2acc = __builtin_fmaf(zn0, zn0, z2acc);
                z2acc = __builtin_fmaf(zn1, zn1, z2acc);
                z2acc = __builtin_fmaf(zn2, zn2, z2acc);
                z2acc = __builtin_fmaf(zn3, zn3, z2acc);
                unsigned h0,l0,h1,l1,h2,l2,h3,l3;
                bsplit(zn0, h0, l0); bsplit(zn1, h1, l1);
                bsplit(zn2, h2, l2); bsplit(zn3, h3, l3);
                hw[ii*2+0] = h0 | (h1 << 16); hw[ii*2+1] = h2 | (h3 << 16);
                lw[ii*2+0] = l0 | (l1 << 16); lw[ii*2+1] = l2 | (l3 << 16);
            }
            o1.x = hw[0]; o1.y = hw[1]; o1.z = hw[2]; o1.w = hw[3];
            o2.x = lw[0]; o2.y = lw[1]; o2.z = lw[2]; o2.w = lw[3];
            int kq = ah * 2 + i2;
            Asl[SL(((0*4 + aw)*2 + art)*4 + kq, ar)] = o1;
            Asl[SL(((1*4 + aw)*2 + art)*4 + kq, ar)] = o2;
        }
        __syncthreads();
        s16x8 afr[2][2];
#pragma unroll
        for (int s = 0; s < 2; s++)
#pragma unroll
            for (int rt = 0; rt < 2; rt++)
                afr[s][rt] = __builtin_bit_cast(s16x8,
                    Asl[SL(((s*4 + w)*2 + rt)*4 + quad, l15)]);
#pragma unroll
        for (int ct = 0; ct < 20; ct++) {
            s16x8 b0 = __builtin_bit_cast(s16x8, Bsl[((0*20 + ct)*4 + quad)*16 + l15]);
            s16x8 b1 = __builtin_bit_cast(s16x8, Bsl[((1*20 + ct)*4 + quad)*16 + l15]);
#pragma unroll
            for (int rt = 0; rt < 2; rt++) {
                acc[rt][ct] = __builtin_amdgcn_mfma_f32_16x16x32_bf16(afr[0][rt], b0, acc[rt][ct], 0, 0, 0);
                acc[rt][ct] = __builtin_amdgcn_mfma_f32_16x16x32_bf16(afr[0][rt], b1, acc[rt][ct], 0, 0, 0);
                acc[rt][ct] = __builtin_amdgcn_mfma_f32_16x16x32_bf16(afr[1][rt], b0, acc[rt][ct], 0, 0, 0);
            }
        }
    }

    // per-row z2: combine the two half-row partials (threads 2r, 2r+1 in same wave)
    {
        float z2pair = z2acc + __shfl_xor(z2acc, 1);
        if (ah == 0) z2l[arow] = z2pair;
    }
    __syncthreads();

    // ---- epilogue: approx argmin + candidate extraction + loss for 1-cand rows --
    double lacc = 0.0;
#pragma unroll
    for (int rt = 0; rt < 2; rt++)
#pragma unroll
    for (int j = 0; j < 4; j++) {
        float m1 = 3.402823466e+38f; int i1 = 0;
#pragma unroll
        for (int ct = 0; ct < 20; ct++) {
            float d2a = e2s[ct * 16 + l15] - 2.0f * acc[rt][ct][j];
            if (d2a < m1) { m1 = d2a; i1 = ct * 16 + l15; }
        }
#pragma unroll
        for (int mm = 1; mm < 16; mm <<= 1) {
            float ov = __shfl_xor(m1, mm);
            int   oi = __shfl_xor(i1, mm);
            if (ov < m1 || (ov == m1 && oi < i1)) { m1 = ov; i1 = oi; }
        }
        float thr = m1 + MARGIN;
        unsigned mask = 0;
#pragma unroll
        for (int ct = 0; ct < 20; ct++) {
            float d2a = e2s[ct * 16 + l15] - 2.0f * acc[rt][ct][j];
            if (d2a <= thr) mask |= (1u << ct);
        }
        int cnt = __popc(mask);
#pragma unroll
        for (int mm = 1; mm < 16; mm <<= 1) cnt += __shfl_xor(cnt, mm);
        int mrow = m0 + w * 32 + rt * 16 + quad * 4 + j;
        unsigned q = (unsigned)mrow * 2u + (unsigned)g;
        unsigned flag = 0;
        if (cnt > 1) {
            if ((i1 & 15) == l15) mask &= ~(1u << (i1 >> 4));   // best is implicit
            int cl2 = __popc(mask);
            int inc = cl2;
#pragma unroll
            for (int off = 1; off < 16; off <<= 1) {
                int t = __shfl_up(inc, off, 16);
                if (l15 >= off) inc += t;
            }
            int pre = inc - cl2;
            if (cnt <= 5) {
                int pos_ = 0;
                if (l15 == 0) pos_ = (int)atomicAdd(cntw, 1u);
                pos_ = __shfl(pos_, 0, 16);
                if ((unsigned)pos_ < LIST_CAP) {
                    flag = 512u;
                    unsigned long long contrib = 0ull;
                    unsigned mm2 = mask; int k = pre;
                    while (mm2) {
                        int ct2 = __ffs(mm2) - 1; mm2 &= mm2 - 1;
                        contrib |= ((unsigned long long)(unsigned)(ct2 * 16 + l15)) << (20 + 9 * k);
                        k++;
                    }
#pragma unroll
                    for (int mm = 1; mm < 16; mm <<= 1)
                        contrib |= __shfl_xor(contrib, mm);
                    if (l15 == 0)
                        listq[pos_] = (unsigned long long)q
                                    | ((unsigned long long)(unsigned)cnt << 17) | contrib;
                }
            } else {
                if (l15 == 0) {
                    unsigned p2 = atomicAdd(cnt2w, 1u);
                    if (p2 < LIST2_CAP) { list2[p2] = q; flag = 512u; }
                }
            }
        }
        if (l15 == 0) {
            unsigned packed = (unsigned)i1 | flag;
            idxl[mrow - m0] = packed;
            if (flag) {
                dout[IDX_OFF + q] = __uint_as_float(packed);
            } else {
                dout[IDX_OFF + q] = (float)i1;
                atomicAdd(&hist[g * Vq + i1], 1u);
                lacc += (double)z2l[mrow - m0] + (double)m1;
            }
        }
    }
#pragma unroll
    for (int mm = 1; mm < 64; mm <<= 1) lacc += __shfl_xor(lacc, mm);
    if (lane == 0) redp[w] = lacc;
    __syncthreads();   // also publishes idxl[] to all threads
    if (tid == 0) ploss[bx] = redp[0] + redp[1] + redp[2] + redp[3];

    // ---- fused gather for unflagged rows (flagged rows written by k_exF) ----
    // 128 rows x 256 floats (this block's g-half) = 32 iters x 1KB/wave coalesced
#pragma unroll
    for (int it = 0; it < 32; it++) {
        int pos = it * 1024 + tid * 4;          // 0..32767 floats
        int row = pos >> 8, d = pos & 255;
        unsigned packed = idxl[row];
        if (!(packed & 512u)) {
            int v = (int)(packed & 511u);
            float4 o = *(const float4*)(emb + ((size_t)(v * 2 + g)) * 256 + d);
            *(float4*)(dout + (size_t)(m0 + row) * Cq + g * CGq + d) = o;
        }
    }
}

// ----- exact resolve among <=5 candidates + full-scan fallback + flagged gather --
__global__ __launch_bounds__(256) void k_exF(const float* __restrict__ emb,
    const float* __restrict__ gw, const float* __restrict__ gb,
    const float* __restrict__ muw, const float* __restrict__ rsw,
    const float* __restrict__ e2w, float* dout,
    unsigned* __restrict__ hist, double* __restrict__ ploss2,
    const unsigned long long* __restrict__ listq, const unsigned* __restrict__ cntw,
    double* __restrict__ lossf,
    const unsigned* __restrict__ cnt2w, const unsigned* __restrict__ list2)
{
    int tid = threadIdx.x, lane = tid & 63;
    int gwid = blockIdx.x * 4 + (tid >> 6);
    int cslot = lane >> 2, j = lane & 3;
    unsigned nn = *cntw; if (nn > LIST_CAP) nn = LIST_CAP;
    int n = (int)nn;
    double lacc = 0.0;
    for (int it = gwid; it < n; it += 2048) {
        unsigned long long e = listq[it];
        unsigned q = (unsigned)(e & 0x1FFFFull);
        int cnt = (int)((e >> 17) & 7u);
        int m = (int)(q >> 1), g = (int)(q & 1u);
        int bg = (m >> 11) * 2 + g;
        float muf = muw[bg], rsf = rsw[bg];
        int v = (int)(__float_as_uint(dout[IDX_OFF + q]) & 511u);
        if (cslot >= 1 && cslot < cnt)
            v = (int)((e >> (20 + 9 * (cslot - 1))) & 511ull);
        const float* zb  = dout + (size_t)m * Cq + g * CGq;
        const float* gwb = gw + g * CGq;
        const float* gbb = gb + g * CGq;
        const float* eb  = emb + ((size_t)v * Gq + g) * CGq;
        float z2p = 0.f, dp = 0.f;
        for (int kc = 0; kc < 16; kc++) {
            int k0 = kc * 16 + j * 4;
            float4 z  = *(const float4*)(zb + k0);
            float4 gv = *(const float4*)(gwb + k0);
            float4 bv = *(const float4*)(gbb + k0);
            float4 e4 = *(const float4*)(eb + k0);
            float zn0 = __fadd_rn(__fmul_rn(__fmul_rn(__fsub_rn(z.x, muf), rsf), gv.x), bv.x);
            float zn1 = __fadd_rn(__fmul_rn(__fmul_rn(__fsub_rn(z.y, muf), rsf), gv.y), bv.y);
            float zn2 = __fadd_rn(__fmul_rn(__fmul_rn(__fsub_rn(z.z, muf), rsf), gv.z), bv.z);
            float zn3 = __fadd_rn(__fmul_rn(__fmul_rn(__fsub_rn(z.w, muf), rsf), gv.w), bv.w);
            z2p = __builtin_fmaf(zn0, zn0, z2p);
            z2p = __builtin_fmaf(zn1, zn1, z2p);
            z2p = __builtin_fmaf(zn2, zn2, z2p);
            z2p = __builtin_fmaf(zn3, zn3, z2p);
            dp = __builtin_fmaf(zn0, e4.x, dp);
            dp = __builtin_fmaf(zn1, e4.y, dp);
            dp = __builtin_fmaf(zn2, e4.z, dp);
            dp = __builtin_fmaf(zn3, e4.w, dp);
        }
        z2p += __shfl_xor(z2p, 1); z2p += __shfl_xor(z2p, 2);
        dp  += __shfl_xor(dp, 1);  dp  += __shfl_xor(dp, 2);
        float d2 = __fadd_rn(__fsub_rn(z2p, 2.0f * dp), e2w[g * Vq + v]);
#pragma unroll
        for (int mm = 4; mm < 64; mm <<= 1) {
            float od = __shfl_xor(d2, mm);
            int   ov = __shfl_xor(v, mm);
            if (od < d2 || (od == d2 && ov < v)) { d2 = od; v = ov; }
        }
        // all lanes hold the winning (d2, v)
        if (lane == 0) {
            dout[IDX_OFF + q] = (float)v;
            atomicAdd(&hist[g * Vq + v], 1u);
            lacc += (double)d2;
        }
        // gather this flagged row-half
        {
            float4 o = *(const float4*)(emb + ((size_t)(v * 2 + g)) * 256 + lane * 4);
            *(float4*)(dout + (size_t)m * Cq + g * CGq + lane * 4) = o;
        }
    }
    if (lane == 0) ploss2[gwid] = lacc;

    // ---- full-scan fallback for >5-candidate rows (expected ~empty) ----
    unsigned nn2 = *cnt2w; if (nn2 > LIST2_CAP) nn2 = LIST2_CAP;
    int n2 = (int)nn2;
    for (int it = gwid; it < n2; it += 2048) {
        int q = (int)list2[it];
        int m = q >> 1, g = q & 1;
        int bg = (m >> 11) * 2 + g;
        float muf = muw[bg], rsf = rsw[bg];
        const float* zb = dout + (size_t)m * Cq + g * CGq;
        int k0 = lane * 4;
        float4 z  = *(const float4*)(zb + k0);
        float4 gv = *(const float4*)(gw + g * CGq + k0);
        float4 bv = *(const float4*)(gb + g * CGq + k0);
        float zn0 = __fadd_rn(__fmul_rn(__fmul_rn(__fsub_rn(z.x, muf), rsf), gv.x), bv.x);
        float zn1 = __fadd_rn(__fmul_rn(__fmul_rn(__fsub_rn(z.y, muf), rsf), gv.y), bv.y);
        float zn2 = __fadd_rn(__fmul_rn(__fmul_rn(__fsub_rn(z.z, muf), rsf), gv.z), bv.z);
        float zn3 = __fadd_rn(__fmul_rn(__fmul_rn(__fsub_rn(z.w, muf), rsf), gv.w), bv.w);
        float s = 0.f;
        for (int kc = 0; kc < 16; kc++) {
            int src = (lane & 3) + kc * 4;
            float a0 = __shfl(zn0, src), a1 = __shfl(zn1, src);
            float a2 = __shfl(zn2, src), a3 = __shfl(zn3, src);
            s = __builtin_fmaf(a0, a0, s);
            s = __builtin_fmaf(a1, a1, s);
            s = __builtin_fmaf(a2, a2, s);
            s = __builtin_fmaf(a3, a3, s);
        }
        s += __shfl_xor(s, 1); s += __shfl_xor(s, 2);
        float z2 = s;
        float m1 = 3.402823466e+38f; int i1 = 0;
        for (int v = 0; v < Vq; v += 2) {
            const float* e0 = emb + ((size_t)v * Gq + g) * CGq + k0;
            float4 ea = *(const float4*)e0;
            float4 eb4 = *(const float4*)(e0 + Gq * CGq);
            float da = zn0 * ea.x;  da = __builtin_fmaf(zn1, ea.y, da);
            da = __builtin_fmaf(zn2, ea.z, da); da = __builtin_fmaf(zn3, ea.w, da);
            float db = zn0 * eb4.x; db = __builtin_fmaf(zn1, eb4.y, db);
            db = __builtin_fmaf(zn2, eb4.z, db); db = __builtin_fmaf(zn3, eb4.w, db);
#pragma unroll
            for (int mm = 1; mm < 64; mm <<= 1) { da += __shfl_xor(da, mm); db += __shfl_xor(db, mm); }
            float d2a = __fadd_rn(__fsub_rn(z2, 2.0f * da), e2w[g * Vq + v]);
            float d2b = __fadd_rn(__fsub_rn(z2, 2.0f * db), e2w[g * Vq + v + 1]);
            if (d2a < m1) { m1 = d2a; i1 = v; }
            if (d2b < m1) { m1 = d2b; i1 = v + 1; }
        }
        if (lane == 0) {
            dout[IDX_OFF + q] = (float)i1;
            atomicAdd(&hist[g * Vq + i1], 1u);
            atomicAdd(lossf, (double)m1);
        }
        // all lanes hold identical (m1, i1): gather this row-half
        {
            float4 o = *(const float4*)(emb + ((size_t)(i1 * 2 + g)) * 256 + lane * 4);
            *(float4*)(dout + (size_t)m * Cq + g * CGq + lane * 4) = o;
        }
    }
}

// ---------------- finalize loss + perplexity ----------------
__global__ __launch_bounds__(256) void k_final(const double* __restrict__ ploss,
                                               const double* __restrict__ ploss2,
                                               const double* __restrict__ lossf,
                                               const unsigned* __restrict__ hist,
                                               float* dout) {
    __shared__ double redl[4], red0[4], red1[4];
    int tid = threadIdx.x;
    double s = 0.0;
    for (int i = tid; i < 512; i += 256) s += ploss[i];
    for (int i = tid; i < 2048; i += 256) s += ploss2[i];
#pragma unroll
    for (int m = 1; m < 64; m <<= 1) s += __shfl_xor(s, m);
    double e0 = 0.0, e1 = 0.0;
    for (int pid = tid; pid < 640; pid += 256) {
        double p = (double)hist[pid] * (1.0 / 32768.0);
        double t = p * log(p + 1e-7);
        if (pid < 320) e0 += t; else e1 += t;
    }
#pragma unroll
    for (int m = 1; m < 64; m <<= 1) { e0 += __shfl_xor(e0, m); e1 += __shfl_xor(e1, m); }
    int lane = tid & 63, wv_ = tid >> 6;
    if (lane == 0) { redl[wv_] = s; red0[wv_] = e0; red1[wv_] = e1; }
    __syncthreads();
    if (tid == 0) {
        double S  = redl[0] + redl[1] + redl[2] + redl[3] + *lossf;
        double E0 = red0[0] + red0[1] + red0[2] + red0[3];
        double E1 = red1[0] + red1[1] + red1[2] + red1[3];
        dout[LOSS_OFF] = (float)(1.25 * S / 16777216.0);
        dout[PPL_OFF]  = (float)(exp(-E0) + exp(-E1));
    }
}

extern "C" void kernel_launch(void* const* d_in, const int* in_sizes, int n_in,
                              void* d_out, int out_size, void* d_ws, size_t ws_size,
                              hipStream_t stream) {
    const float* x   = (const float*)d_in[0];
    const float* w   = (const float*)d_in[1];
    const float* gw  = (const float*)d_in[2];
    const float* gb  = (const float*)d_in[3];
    const float* emb = (const float*)d_in[4];
    float* dout = (float*)d_out;
    char* ws = (char*)d_ws;
    double* pconv   = (double*)(ws + WS_PCONV);
    double* ploss   = (double*)(ws + WS_PLOSS);
    float* muw      = (float*)(ws + WS_MU);
    float* rsw      = (float*)(ws + WS_RS);
    float* e2w      = (float*)(ws + WS_E2);
    double* lossf   = (double*)(ws + WS_LOSSF);
    unsigned* cntw  = (unsigned*)(ws + WS_CNT);
    unsigned* cnt2w = (unsigned*)(ws + WS_CNT2);
    unsigned* hist  = (unsigned*)(ws + WS_HIST);
    double* ploss2  = (double*)(ws + WS_PL2);
    unsigned* list2 = (unsigned*)(ws + WS_LIST2);
    unsigned char* wsp = (unsigned char*)(ws + WS_WSP);
    unsigned long long* listq = (unsigned long long*)(ws + WS_LISTQ);
    unsigned char* esp = (unsigned char*)(ws + WS_ESP);

    hipMemsetAsync(ws + WS_LOSSF, 0, 2576, stream);   // lossf + cnt + cnt2 + hist
    k_prep<<<304, 256, 0, stream>>>(w, emb, wsp, esp, e2w);
    k_convM<<<512, 256, 0, stream>>>(x, wsp, dout, pconv);    // ze staged in d_out
    k_stats<<<1, 256, 0, stream>>>(pconv, muw, rsw);
    k_distA<<<512, 256, 0, stream>>>(esp, gw, gb, muw, rsw, e2w, emb, dout,
                                     cntw, cnt2w, listq, list2, hist, ploss);
    k_exF<<<512, 256, 0, stream>>>(emb, gw, gb, muw, rsw, e2w, dout, hist, ploss2,
                                   listq, cntw, lossf, cnt2w, list2);
    k_final<<<1, 256, 0, stream>>>(ploss, ploss2, lossf, hist, dout);
}